// Round 1
// baseline (572.839 us; speedup 1.0000x reference)
//
#include <hip/hip_runtime.h>
#include <math.h>

#define YD 512
#define XD 64
#define KK 16
#define R3 16

__device__ __forceinline__ float wave_sum(float v) {
#pragma unroll
    for (int off = 32; off > 0; off >>= 1) v += __shfl_xor(v, off, 64);
    return v;
}

__device__ __forceinline__ float softplusf(float x) {
    // max(x,0) + log(1+exp(-|x|)); __logf arg in [1,2] -> accurate enough here
    return fmaxf(x, 0.0f) + __logf(1.0f + __expf(-fabsf(x)));
}

// ---------------- Kernel 1: encoder GEMM (Y @ We_mu / We_sig) ----------------
__global__ __launch_bounds__(256) void encoder_kernel(
    const float* __restrict__ Y, const float* __restrict__ We_mu,
    const float* __restrict__ be_mu, const float* __restrict__ We_sig,
    const float* __restrict__ be_sig, float* __restrict__ enc_mu,
    float* __restrict__ enc_sig)
{
    __shared__ float Ys[16][YD + 4];
    const int t = threadIdx.x;
    const int n0 = blockIdx.x * 16;

    // stage 16 rows of Y into LDS (float4 coalesced)
    const float4* Y4 = (const float4*)(Y + (size_t)n0 * YD);
#pragma unroll
    for (int i = 0; i < 8; ++i) {
        int f = t + i * 256;          // 0..2047
        int r = f >> 7;               // 128 float4 per row
        int c4 = f & 127;
        float4 v = Y4[r * 128 + c4];
        *((float4*)&Ys[r][c4 * 4]) = v;
    }
    __syncthreads();

    const int c4 = (t & 15) * 4;      // 4 consecutive output cols
    const int r = t >> 4;             // row within tile (0..15)
    float amu[4] = {0.f, 0.f, 0.f, 0.f};
    float asg[4] = {0.f, 0.f, 0.f, 0.f};
    const float* wm = We_mu + c4;
    const float* wsp = We_sig + c4;

#pragma unroll 4
    for (int k = 0; k < YD; ++k) {
        float4 wmu = *(const float4*)(wm + k * XD);
        float4 wsg = *(const float4*)(wsp + k * XD);
        float y = Ys[r][k];
        amu[0] = fmaf(y, wmu.x, amu[0]);
        amu[1] = fmaf(y, wmu.y, amu[1]);
        amu[2] = fmaf(y, wmu.z, amu[2]);
        amu[3] = fmaf(y, wmu.w, amu[3]);
        asg[0] = fmaf(y, wsg.x, asg[0]);
        asg[1] = fmaf(y, wsg.y, asg[1]);
        asg[2] = fmaf(y, wsg.z, asg[2]);
        asg[3] = fmaf(y, wsg.w, asg[3]);
    }

    const int n = n0 + r;
    float4 bm = *(const float4*)(be_mu + c4);
    float4 bs = *(const float4*)(be_sig + c4);
    float4 om, os;
    om.x = amu[0] + bm.x;  om.y = amu[1] + bm.y;
    om.z = amu[2] + bm.z;  om.w = amu[3] + bm.w;
    os.x = softplusf(asg[0] + bs.x) + 1e-3f;
    os.y = softplusf(asg[1] + bs.y) + 1e-3f;
    os.z = softplusf(asg[2] + bs.z) + 1e-3f;
    os.w = softplusf(asg[3] + bs.w) + 1e-3f;
    *(float4*)(enc_mu + (size_t)n * XD + c4) = om;
    *(float4*)(enc_sig + (size_t)n * XD + c4) = os;
}

// ---------------- Kernel 2: responsibilities + gumbel mixing + losses 2/3/4/5 ----------------
__global__ __launch_bounds__(256) void middle_kernel(
    const float* __restrict__ enc_mu_g, const float* __restrict__ enc_sig_g,
    const float* __restrict__ phi_mus, const float* __restrict__ phi_sigs,
    const float* __restrict__ phi_logits,
    const float* __restrict__ theta_mus, const float* __restrict__ theta_sigs,
    const float* __restrict__ theta_logits,
    const float* __restrict__ u_noise, const float* __restrict__ eps_noise,
    const float* __restrict__ temperature,
    float* __restrict__ x_samp, double* __restrict__ accum, int N, int S)
{
    const int wid = blockIdx.x * (blockDim.x >> 6) + (threadIdx.x >> 6);
    if (wid >= N) return;
    const int n = wid;
    const int d = threadIdx.x & 63;

    const float em = enc_mu_g[(size_t)n * XD + d];
    const float es = enc_sig_g[(size_t)n * XD + d];
    const float inv_es = 1.0f / es;
    const float log_es = __logf(es);
    const float invT = 1.0f / temperature[0];

    float pm[KK], psg[KK], tm[KK], tsg[KK];
#pragma unroll
    for (int k = 0; k < KK; ++k) {
        pm[k]  = phi_mus[k * XD + d];
        psg[k] = phi_sigs[k * XD + d];
        tm[k]  = theta_mus[k * XD + d];
        tsg[k] = theta_sigs[k * XD + d];
    }

    // z_logits up to an additive k-independent constant (cancels in log_softmax):
    // zl[k] = phi_logits[k] + sum_d( -0.5*((em-pm)/std)^2 - log(std) )
    float zl[KK];
#pragma unroll
    for (int k = 0; k < KK; ++k) {
        float sd = es + psg[k];
        float diff = (em - pm[k]) / sd;
        float r = fmaf(-0.5f * diff, diff, -__logf(sd));
        r = wave_sum(r);
        zl[k] = r + phi_logits[k];
    }
    // log_softmax over k
    float mx = zl[0];
#pragma unroll
    for (int k = 1; k < KK; ++k) mx = fmaxf(mx, zl[k]);
    float sum = 0.f;
#pragma unroll
    for (int k = 0; k < KK; ++k) sum += __expf(zl[k] - mx);
    float lse = mx + __logf(sum);
#pragma unroll
    for (int k = 0; k < KK; ++k) zl[k] -= lse;      // now z_log_probs

    // loss5 term for this n: log(sum exp(z_log_probs)) (numerically ~0)
    float m3 = zl[0];
#pragma unroll
    for (int k = 1; k < KK; ++k) m3 = fmaxf(m3, zl[k]);
    float s3 = 0.f;
#pragma unroll
    for (int k = 0; k < KK; ++k) s3 += __expf(zl[k] - m3);
    float l5 = m3 + __logf(s3);

    // theta logits + logsumexp (dot(log_softmax(t),z) = dot(t,z) - lse_t)
    float tl[KK];
#pragma unroll
    for (int k = 0; k < KK; ++k) tl[k] = theta_logits[k];
    float mt2 = tl[0];
#pragma unroll
    for (int k = 1; k < KK; ++k) mt2 = fmaxf(mt2, tl[k]);
    float st2 = 0.f;
#pragma unroll
    for (int k = 0; k < KK; ++k) st2 += __expf(tl[k] - mt2);
    const float lset = mt2 + __logf(st2);

    // per-cluster posterior
    float mu_t[KK], Sg_t[KK];
#pragma unroll
    for (int k = 0; k < KK; ++k) {
        float ig = 1.0f / psg[k];
        float Sg = 1.0f / (inv_es + ig);
        Sg_t[k] = Sg;
        mu_t[k] = Sg * fmaf(inv_es, em, ig * pm[k]);
    }

    const float C234 = 0.5f * XD * 1.8378770664093453f;  // net +0.5*Xd*log(2pi)
    float acc234 = 0.f;
    const float* urow = u_noise + (size_t)(n * S) * KK;
    const float* erow = eps_noise + (size_t)(n * S) * XD;
    float* xrow = x_samp + (size_t)(n * S) * XD;

    for (int s = 0; s < S; ++s) {
        float lg[KK];
        float mg = -1e30f;
#pragma unroll
        for (int k = 0; k < KK; ++k) {
            float u = urow[s * KK + k];
            float g = -__logf(-__logf(u));
            lg[k] = (zl[k] + g) * invT;
            mg = fmaxf(mg, lg[k]);
        }
        float zsum = 0.f;
        float ms = 0.f, Ss = 0.f, tmu = 0.f, tsig = 0.f, pmu = 0.f, psig = 0.f;
        float dz = 0.f, dth = 0.f;
#pragma unroll
        for (int k = 0; k < KK; ++k) {
            float e = __expf(lg[k] - mg);
            zsum += e;
            ms   = fmaf(e, mu_t[k], ms);
            Ss   = fmaf(e, Sg_t[k], Ss);
            tmu  = fmaf(e, tm[k], tmu);
            tsig = fmaf(e, tsg[k], tsig);
            pmu  = fmaf(e, pm[k], pmu);
            psig = fmaf(e, psg[k], psig);
            dz   = fmaf(e, zl[k], dz);
            dth  = fmaf(e, tl[k], dth);
        }
        float rn = 1.0f / zsum;
        ms *= rn; Ss *= rn; tmu *= rn; tsig *= rn; pmu *= rn; psig *= rn;
        dz *= rn; dth *= rn;

        float ep = erow[s * XD + d];
        float x = fmaf(sqrtf(Ss), ep, ms);
        xrow[s * XD + d] = x;

        // loss2 + loss3 + loss4 per-lane reduction value
        float de  = (x - em) * inv_es;
        float dt2 = (x - tmu) / tsig;
        float dp  = (x - pmu) / psig;
        float r = 0.5f * (de * de - dt2 * dt2 + dp * dp)
                + log_es - __logf(tsig) + __logf(psig);
        r = wave_sum(r);
        acc234 += r + C234 + (dth - lset) - dz;
    }

    if (d == 0) {
        atomicAdd(accum + 0, (double)acc234);
        atomicAdd(accum + 1, (double)l5);
    }
}

// ---------------- Kernel 3: decoder GEMM + fused loss1 ----------------
__global__ __launch_bounds__(512) void decoder_kernel(
    const float* __restrict__ x_samp, const float* __restrict__ Wd_mu,
    const float* __restrict__ bd_mu, const float* __restrict__ Wd_sig,
    const float* __restrict__ bd_sig, const float* __restrict__ Y,
    double* __restrict__ accum, int S)
{
    __shared__ float xsT[XD * R3];   // [d][r] transposed tile
    __shared__ float wpart[8];
    const int t = threadIdx.x;
    const int row0 = blockIdx.x * R3;

#pragma unroll
    for (int i = 0; i < 2; ++i) {
        int f = t + i * 512;          // 0..1023 = 16 rows x 64 dims
        int r = f >> 6, d = f & 63;
        xsT[d * R3 + r] = x_samp[(size_t)(row0 + r) * XD + d];
    }
    __syncthreads();

    const int c = t;                  // output column 0..511
    float amu[R3], asg[R3];
    const float bm = bd_mu[c], bs = bd_sig[c];
#pragma unroll
    for (int r = 0; r < R3; ++r) { amu[r] = bm; asg[r] = bs; }

    for (int dd = 0; dd < XD; ++dd) {
        float wm  = Wd_mu[dd * YD + c];
        float ws2 = Wd_sig[dd * YD + c];
        const float4* xv = (const float4*)(xsT + dd * R3);
        float4 a0 = xv[0], a1 = xv[1], a2 = xv[2], a3 = xv[3];
        float xr[R3];
        xr[0] = a0.x; xr[1] = a0.y; xr[2] = a0.z; xr[3] = a0.w;
        xr[4] = a1.x; xr[5] = a1.y; xr[6] = a1.z; xr[7] = a1.w;
        xr[8] = a2.x; xr[9] = a2.y; xr[10] = a2.z; xr[11] = a2.w;
        xr[12] = a3.x; xr[13] = a3.y; xr[14] = a3.z; xr[15] = a3.w;
#pragma unroll
        for (int r = 0; r < R3; ++r) {
            amu[r] = fmaf(xr[r], wm, amu[r]);
            asg[r] = fmaf(xr[r], ws2, asg[r]);
        }
    }

    float part = 0.f;
#pragma unroll
    for (int r = 0; r < R3; ++r) {
        int n = (row0 + r) / S;
        float Yv = Y[(size_t)n * YD + c];
        float sig = softplusf(asg[r]) + 1e-3f;
        float diff = (Yv - amu[r]) / sig;
        part = fmaf(-0.5f * diff, diff, part) - __logf(sig);
    }
    part = wave_sum(part);
    if ((t & 63) == 0) wpart[t >> 6] = part;
    __syncthreads();
    if (t == 0) {
        float tot = 0.f;
#pragma unroll
        for (int w = 0; w < 8; ++w) tot += wpart[w];
        atomicAdd(accum + 2, (double)tot);
    }
}

// ---------------- Kernel 4: finalize ----------------
__global__ void finalize_kernel(const double* __restrict__ accum,
                                float* __restrict__ out, int NS, int S)
{
    double l234 = accum[0];
    double l5 = accum[1];
    double l1 = accum[2] + (double)NS * (-0.5 * (double)YD * 1.8378770664093453);
    out[0] = (float)(-((l1 + l234) / (double)S + l5));
}

extern "C" void kernel_launch(void* const* d_in, const int* in_sizes, int n_in,
                              void* d_out, int out_size, void* d_ws, size_t ws_size,
                              hipStream_t stream) {
    const float* Y            = (const float*)d_in[0];
    const float* We_mu        = (const float*)d_in[1];
    const float* be_mu        = (const float*)d_in[2];
    const float* We_sig       = (const float*)d_in[3];
    const float* be_sig       = (const float*)d_in[4];
    const float* Wd_mu        = (const float*)d_in[5];
    const float* bd_mu        = (const float*)d_in[6];
    const float* Wd_sig       = (const float*)d_in[7];
    const float* bd_sig       = (const float*)d_in[8];
    const float* phi_mus      = (const float*)d_in[9];
    const float* phi_sigs     = (const float*)d_in[10];
    const float* phi_logits   = (const float*)d_in[11];
    const float* theta_mus    = (const float*)d_in[12];
    const float* theta_sigs   = (const float*)d_in[13];
    const float* theta_logits = (const float*)d_in[14];
    const float* u_noise      = (const float*)d_in[15];
    const float* eps_noise    = (const float*)d_in[16];
    const float* temperature  = (const float*)d_in[17];

    const int N = in_sizes[0] / YD;           // 8192
    const int S = in_sizes[15] / (N * KK);    // 10
    const int NS = N * S;

    double* accum = (double*)d_ws;
    float* enc_mu  = (float*)((char*)d_ws + 64);
    float* enc_sig = enc_mu + (size_t)N * XD;
    float* x_samp  = enc_sig + (size_t)N * XD;

    hipMemsetAsync(accum, 0, 64, stream);

    encoder_kernel<<<N / 16, 256, 0, stream>>>(Y, We_mu, be_mu, We_sig, be_sig,
                                               enc_mu, enc_sig);
    middle_kernel<<<N / 4, 256, 0, stream>>>(enc_mu, enc_sig, phi_mus, phi_sigs,
                                             phi_logits, theta_mus, theta_sigs,
                                             theta_logits, u_noise, eps_noise,
                                             temperature, x_samp, accum, N, S);
    decoder_kernel<<<NS / R3, 512, 0, stream>>>(x_samp, Wd_mu, bd_mu, Wd_sig,
                                                bd_sig, Y, accum, S);
    finalize_kernel<<<1, 1, 0, stream>>>(accum, (float*)d_out, NS, S);
}

// Round 2
// 375.706 us; speedup vs baseline: 1.5247x; 1.5247x over previous
//
#include <hip/hip_runtime.h>
#include <math.h>

#define YD 512
#define XD 64
#define KK 16

typedef __attribute__((ext_vector_type(8))) short short8;
typedef __attribute__((ext_vector_type(4))) float f32x4;

__device__ __forceinline__ float wave_sum(float v) {
#pragma unroll
    for (int off = 32; off > 0; off >>= 1) v += __shfl_xor(v, off, 64);
    return v;
}

__device__ __forceinline__ float softplusf(float x) {
    return fmaxf(x, 0.0f) + __logf(1.0f + __expf(-fabsf(x)));
}

__device__ __forceinline__ unsigned short f32_to_bf16(float f) {
    union { float f; unsigned int u; } v; v.f = f;
    unsigned int r = v.u + 0x7fffu + ((v.u >> 16) & 1u);
    return (unsigned short)(r >> 16);
}

// ---------------- Kernel 0: prep — swizzle decoder weights to bf16 frag layout,
// inv phi_sigs table, theta logsumexp ----------------
// swz layout: e = ((tg*8 + q)*16 + n)*8 + j  -> W[(q*8+j)*512 + tg*16 + n]
__global__ __launch_bounds__(256) void prep_kernel(
    const float* __restrict__ Wd_mu, const float* __restrict__ Wd_sig,
    const float* __restrict__ phi_sigs, const float* __restrict__ theta_logits,
    unsigned short* __restrict__ wmu_s, unsigned short* __restrict__ wsg_s,
    float* __restrict__ inv_ps, float* __restrict__ lsetp)
{
    int idx = blockIdx.x * 256 + threadIdx.x;
    if (idx < 65536) {
        int mat = idx >> 15;            // 0: mu, 1: sig
        int e = idx & 32767;
        int j = e & 7;
        int n = (e >> 3) & 15;
        int q = (e >> 7) & 7;
        int tg = e >> 10;
        int k = q * 8 + j;
        int col = tg * 16 + n;
        const float* W = mat ? Wd_sig : Wd_mu;
        unsigned short* o = mat ? wsg_s : wmu_s;
        o[e] = f32_to_bf16(W[k * YD + col]);
    } else if (idx < 65536 + 1024) {
        int e = idx - 65536;
        inv_ps[e] = 1.0f / phi_sigs[e];
    } else if (idx == 65536 + 1024) {
        float mt = theta_logits[0];
        for (int k = 1; k < KK; ++k) mt = fmaxf(mt, theta_logits[k]);
        float st = 0.f;
        for (int k = 0; k < KK; ++k) st += __expf(theta_logits[k] - mt);
        lsetp[0] = mt + __logf(st);
    }
}

// ---------------- Kernel 1: encoder GEMM (Y @ We_mu / We_sig) ----------------
__global__ __launch_bounds__(256) void encoder_kernel(
    const float* __restrict__ Y, const float* __restrict__ We_mu,
    const float* __restrict__ be_mu, const float* __restrict__ We_sig,
    const float* __restrict__ be_sig, float* __restrict__ enc_mu,
    float* __restrict__ enc_sig)
{
    __shared__ float Ys[16][YD + 4];
    const int t = threadIdx.x;
    const int n0 = blockIdx.x * 16;

    const float4* Y4 = (const float4*)(Y + (size_t)n0 * YD);
#pragma unroll
    for (int i = 0; i < 8; ++i) {
        int f = t + i * 256;
        int r = f >> 7;
        int c4 = f & 127;
        float4 v = Y4[r * 128 + c4];
        *((float4*)&Ys[r][c4 * 4]) = v;
    }
    __syncthreads();

    const int c4 = (t & 15) * 4;
    const int r = t >> 4;
    float amu[4] = {0.f, 0.f, 0.f, 0.f};
    float asg[4] = {0.f, 0.f, 0.f, 0.f};
    const float* wm = We_mu + c4;
    const float* wsp = We_sig + c4;

#pragma unroll 4
    for (int k = 0; k < YD; ++k) {
        float4 wmu = *(const float4*)(wm + k * XD);
        float4 wsg = *(const float4*)(wsp + k * XD);
        float y = Ys[r][k];
        amu[0] = fmaf(y, wmu.x, amu[0]);
        amu[1] = fmaf(y, wmu.y, amu[1]);
        amu[2] = fmaf(y, wmu.z, amu[2]);
        amu[3] = fmaf(y, wmu.w, amu[3]);
        asg[0] = fmaf(y, wsg.x, asg[0]);
        asg[1] = fmaf(y, wsg.y, asg[1]);
        asg[2] = fmaf(y, wsg.z, asg[2]);
        asg[3] = fmaf(y, wsg.w, asg[3]);
    }

    const int n = n0 + r;
    float4 bm = *(const float4*)(be_mu + c4);
    float4 bs = *(const float4*)(be_sig + c4);
    float4 om, os;
    om.x = amu[0] + bm.x;  om.y = amu[1] + bm.y;
    om.z = amu[2] + bm.z;  om.w = amu[3] + bm.w;
    os.x = softplusf(asg[0] + bs.x) + 1e-3f;
    os.y = softplusf(asg[1] + bs.y) + 1e-3f;
    os.z = softplusf(asg[2] + bs.z) + 1e-3f;
    os.w = softplusf(asg[3] + bs.w) + 1e-3f;
    *(float4*)(enc_mu + (size_t)n * XD + c4) = om;
    *(float4*)(enc_sig + (size_t)n * XD + c4) = os;
}

// ---------------- Kernel 2a: responsibilities (z_log_probs) + loss5 ----------------
__global__ __launch_bounds__(256) void resp_kernel(
    const float* __restrict__ enc_mu_g, const float* __restrict__ enc_sig_g,
    const float* __restrict__ phi_mus, const float* __restrict__ phi_sigs,
    const float* __restrict__ phi_logits,
    float* __restrict__ zlp, double* __restrict__ slotsL5)
{
    __shared__ float red[4];
    const int wv = threadIdx.x >> 6;
    const int n = blockIdx.x * 4 + wv;
    const int d = threadIdx.x & 63;

    const float em = enc_mu_g[(size_t)n * XD + d];
    const float es = enc_sig_g[(size_t)n * XD + d];

    float zl[KK];
#pragma unroll
    for (int k = 0; k < KK; ++k) {
        float sd = es + phi_sigs[k * XD + d];
        float diff = (em - phi_mus[k * XD + d]) / sd;
        float r = fmaf(-0.5f * diff, diff, -__logf(sd));
        r = wave_sum(r);
        zl[k] = r + phi_logits[k];
    }
    float mx = zl[0];
#pragma unroll
    for (int k = 1; k < KK; ++k) mx = fmaxf(mx, zl[k]);
    float sum = 0.f;
#pragma unroll
    for (int k = 0; k < KK; ++k) sum += __expf(zl[k] - mx);
    float lse = mx + __logf(sum);
#pragma unroll
    for (int k = 0; k < KK; ++k) zl[k] -= lse;

    // loss5 term: log(sum exp(z_log_probs))
    float m3 = zl[0];
#pragma unroll
    for (int k = 1; k < KK; ++k) m3 = fmaxf(m3, zl[k]);
    float s3 = 0.f;
#pragma unroll
    for (int k = 0; k < KK; ++k) s3 += __expf(zl[k] - m3);
    float l5 = m3 + __logf(s3);

    // write zlp[n][d] for d<16 (select zl[d] via cndmask chain)
    float v = zl[0];
#pragma unroll
    for (int k = 1; k < KK; ++k) v = (d == k) ? zl[k] : v;
    if (d < KK) zlp[(size_t)n * KK + d] = v;

    if (d == 0) red[wv] = l5;
    __syncthreads();
    if (threadIdx.x == 0) {
        float t = red[0] + red[1] + red[2] + red[3];
        atomicAdd(slotsL5 + (blockIdx.x & 63), (double)t);
    }
}

// ---------------- Kernel 2b: gumbel sampling + losses 2/3/4, one wave per (n,s) ----------------
__global__ __launch_bounds__(256, 4) void sample_kernel(
    const float* __restrict__ enc_mu_g, const float* __restrict__ enc_sig_g,
    const float* __restrict__ zlp,
    const float* __restrict__ phi_mus, const float* __restrict__ phi_sigs,
    const float* __restrict__ inv_ps,
    const float* __restrict__ theta_mus, const float* __restrict__ theta_sigs,
    const float* __restrict__ theta_logits, const float* __restrict__ lsetp,
    const float* __restrict__ u_noise, const float* __restrict__ eps_noise,
    const float* __restrict__ temperature,
    unsigned short* __restrict__ x_bf16, double* __restrict__ slots234, int S)
{
    __shared__ float red[4];
    const int wv = threadIdx.x >> 6;
    const int wid = blockIdx.x * 4 + wv;   // = n*S + s
    const int d = threadIdx.x & 63;
    const int n = wid / S;

    const float em = enc_mu_g[(size_t)n * XD + d];
    const float es = enc_sig_g[(size_t)n * XD + d];
    const float inv_es = 1.0f / es;
    const float log_es = __logf(es);
    const float invT = 1.0f / temperature[0];
    const float lset = lsetp[0];

    float zl[KK], lg[KK];
    float mg = -1e30f;
    const float* up = u_noise + (size_t)wid * KK;
    const float* zp = zlp + (size_t)n * KK;
#pragma unroll
    for (int k = 0; k < KK; ++k) {
        zl[k] = zp[k];
        float u = up[k];
        float g = -__logf(-__logf(u));
        lg[k] = (zl[k] + g) * invT;
        mg = fmaxf(mg, lg[k]);
    }

    float zsum = 0.f, ms = 0.f, Ss = 0.f, tmu = 0.f, tsig = 0.f;
    float pmu = 0.f, psig = 0.f, dz = 0.f, dth = 0.f;
#pragma unroll
    for (int k = 0; k < KK; ++k) {
        float pmv = phi_mus[k * XD + d];
        float psv = phi_sigs[k * XD + d];
        float ig  = inv_ps[k * XD + d];
        float Sg  = 1.0f / (inv_es + ig);
        float mu  = Sg * fmaf(inv_es, em, ig * pmv);
        float e   = __expf(lg[k] - mg);
        zsum += e;
        ms   = fmaf(e, mu, ms);
        Ss   = fmaf(e, Sg, Ss);
        tmu  = fmaf(e, theta_mus[k * XD + d], tmu);
        tsig = fmaf(e, theta_sigs[k * XD + d], tsig);
        pmu  = fmaf(e, pmv, pmu);
        psig = fmaf(e, psv, psig);
        dz   = fmaf(e, zl[k], dz);
        dth  = fmaf(e, theta_logits[k], dth);
    }
    float rn = 1.0f / zsum;
    ms *= rn; Ss *= rn; tmu *= rn; tsig *= rn; pmu *= rn; psig *= rn;
    dz *= rn; dth *= rn;

    float ep = eps_noise[(size_t)wid * XD + d];
    float x = fmaf(sqrtf(Ss), ep, ms);
    x_bf16[(size_t)wid * XD + d] = f32_to_bf16(x);

    float de  = (x - em) * inv_es;
    float dt2 = (x - tmu) / tsig;
    float dp  = (x - pmu) / psig;
    float r = 0.5f * (de * de - dt2 * dt2 + dp * dp)
            + log_es - __logf(tsig) + __logf(psig);
    r = wave_sum(r);

    const float C234 = 0.5f * XD * 1.8378770664093453f;
    float acc = r + C234 + (dth - lset) - dz;

    if (d == 0) red[wv] = acc;
    __syncthreads();
    if (threadIdx.x == 0) {
        float t = red[0] + red[1] + red[2] + red[3];
        atomicAdd(slots234 + (blockIdx.x & 63), (double)t);
    }
}

// ---------------- Kernel 3: decoder via bf16 MFMA + fused loss1 ----------------
// block = 256 (4 waves); block tile = 64 rows x 64 cols; wave tile = 16 rows x 64 cols
__global__ __launch_bounds__(256) void decoder_mfma(
    const unsigned short* __restrict__ xb,    // [NS][64] bf16
    const unsigned short* __restrict__ wmu_s, // swizzled bf16 [32768]
    const unsigned short* __restrict__ wsg_s,
    const float* __restrict__ bd_mu, const float* __restrict__ bd_sig,
    const float* __restrict__ Y, double* __restrict__ slots1,
    unsigned int magicS)
{
    __shared__ float red[4];
    const int t = threadIdx.x;
    const int w = t >> 6;
    const int lane = t & 63;
    const int l16 = lane & 15;
    const int quad = lane >> 4;
    const int mb = blockIdx.x >> 3;     // row block (64 rows)
    const int nb = blockIdx.x & 7;      // col block (64 cols)

    const int mrow = mb * 64 + w * 16 + l16;
    const short8 a0 = *(const short8*)(xb + (size_t)mrow * XD + quad * 8);
    const short8 a1 = *(const short8*)(xb + (size_t)mrow * XD + 32 + quad * 8);

    f32x4 accmu[4], accsg[4];
#pragma unroll
    for (int tt = 0; tt < 4; ++tt) {
        accmu[tt] = (f32x4){0.f, 0.f, 0.f, 0.f};
        accsg[tt] = (f32x4){0.f, 0.f, 0.f, 0.f};
    }

#pragma unroll
    for (int tt = 0; tt < 4; ++tt) {
        int tg = nb * 4 + tt;
        int boff = ((tg * 8 + quad) * 16 + l16) * 8;
        short8 b0 = *(const short8*)(wmu_s + boff);
        short8 b1 = *(const short8*)(wmu_s + boff + 512);
        short8 c0 = *(const short8*)(wsg_s + boff);
        short8 c1 = *(const short8*)(wsg_s + boff + 512);
        accmu[tt] = __builtin_amdgcn_mfma_f32_16x16x32_bf16(a0, b0, accmu[tt], 0, 0, 0);
        accmu[tt] = __builtin_amdgcn_mfma_f32_16x16x32_bf16(a1, b1, accmu[tt], 0, 0, 0);
        accsg[tt] = __builtin_amdgcn_mfma_f32_16x16x32_bf16(a0, c0, accsg[tt], 0, 0, 0);
        accsg[tt] = __builtin_amdgcn_mfma_f32_16x16x32_bf16(a1, c1, accsg[tt], 0, 0, 0);
    }

    float part = 0.f;
    const int m_base = mb * 64 + w * 16 + quad * 4;
#pragma unroll
    for (int tt = 0; tt < 4; ++tt) {
        int col = (nb * 4 + tt) * 16 + l16;
        float bmv = bd_mu[col], bsv = bd_sig[col];
#pragma unroll
        for (int r = 0; r < 4; ++r) {
            int row = m_base + r;
            unsigned int ny = (unsigned int)(((unsigned long long)(unsigned int)row * magicS) >> 35);
            float Yv = Y[(size_t)ny * YD + col];
            float sig = softplusf(accsg[tt][r] + bsv) + 1e-3f;
            float diff = (Yv - (accmu[tt][r] + bmv)) / sig;
            part = fmaf(-0.5f * diff, diff, part) - __logf(sig);
        }
    }
    part = wave_sum(part);
    if (lane == 0) red[w] = part;
    __syncthreads();
    if (t == 0) {
        atomicAdd(slots1 + (blockIdx.x & 63),
                  (double)(red[0] + red[1] + red[2] + red[3]));
    }
}

// ---------------- Kernel 4: finalize ----------------
__global__ void finalize_kernel(const double* __restrict__ slots,
                                float* __restrict__ out, int NS, int S)
{
    double l234 = 0.0, l5 = 0.0, l1 = 0.0;
    for (int i = 0; i < 64; ++i) {
        l234 += slots[i];
        l5   += slots[64 + i];
        l1   += slots[128 + i];
    }
    l1 += (double)NS * (-0.5 * (double)YD * 1.8378770664093453);
    out[0] = (float)(-((l1 + l234) / (double)S + l5));
}

extern "C" void kernel_launch(void* const* d_in, const int* in_sizes, int n_in,
                              void* d_out, int out_size, void* d_ws, size_t ws_size,
                              hipStream_t stream) {
    const float* Y            = (const float*)d_in[0];
    const float* We_mu        = (const float*)d_in[1];
    const float* be_mu        = (const float*)d_in[2];
    const float* We_sig       = (const float*)d_in[3];
    const float* be_sig       = (const float*)d_in[4];
    const float* Wd_mu        = (const float*)d_in[5];
    const float* bd_mu        = (const float*)d_in[6];
    const float* Wd_sig       = (const float*)d_in[7];
    const float* bd_sig       = (const float*)d_in[8];
    const float* phi_mus      = (const float*)d_in[9];
    const float* phi_sigs     = (const float*)d_in[10];
    const float* phi_logits   = (const float*)d_in[11];
    const float* theta_mus    = (const float*)d_in[12];
    const float* theta_sigs   = (const float*)d_in[13];
    const float* theta_logits = (const float*)d_in[14];
    const float* u_noise      = (const float*)d_in[15];
    const float* eps_noise    = (const float*)d_in[16];
    const float* temperature  = (const float*)d_in[17];

    const int N = in_sizes[0] / YD;           // 8192
    const int S = in_sizes[15] / (N * KK);    // 10
    const int NS = N * S;
    const unsigned int magicS =
        (unsigned int)((((unsigned long long)1 << 35) + S - 1) / (unsigned long long)S);

    // workspace layout
    char* base = (char*)d_ws;
    double* slots = (double*)base;                       // 192 doubles (3 x 64)
    float* enc_mu  = (float*)(base + 2048);              // N*64
    float* enc_sig = enc_mu + (size_t)N * XD;            // N*64
    float* zlp     = enc_sig + (size_t)N * XD;           // N*16
    float* inv_ps  = zlp + (size_t)N * KK;               // 1024
    float* lsetp   = inv_ps + 1024;                      // 1 (+pad)
    unsigned short* xb    = (unsigned short*)(lsetp + 16);   // NS*64 bf16
    unsigned short* wmu_s = xb + (size_t)NS * XD;            // 32768
    unsigned short* wsg_s = wmu_s + 32768;                   // 32768

    hipMemsetAsync(slots, 0, 2048, stream);

    prep_kernel<<<261, 256, 0, stream>>>(Wd_mu, Wd_sig, phi_sigs, theta_logits,
                                         wmu_s, wsg_s, inv_ps, lsetp);
    encoder_kernel<<<N / 16, 256, 0, stream>>>(Y, We_mu, be_mu, We_sig, be_sig,
                                               enc_mu, enc_sig);
    resp_kernel<<<N / 4, 256, 0, stream>>>(enc_mu, enc_sig, phi_mus, phi_sigs,
                                           phi_logits, zlp, slots + 64);
    sample_kernel<<<NS / 4, 256, 0, stream>>>(enc_mu, enc_sig, zlp, phi_mus,
                                              phi_sigs, inv_ps, theta_mus,
                                              theta_sigs, theta_logits, lsetp,
                                              u_noise, eps_noise, temperature,
                                              xb, slots, S);
    decoder_mfma<<<(NS / 64) * (YD / 64), 256, 0, stream>>>(
        xb, wmu_s, wsg_s, bd_mu, bd_sig, Y, slots + 128, magicS);
    finalize_kernel<<<1, 1, 0, stream>>>(slots, (float*)d_out, NS, S);
}

// Round 3
// 290.381 us; speedup vs baseline: 1.9727x; 1.2938x over previous
//
#include <hip/hip_runtime.h>
#include <math.h>

#define YD 512
#define XD 64
#define KK 16

typedef __attribute__((ext_vector_type(8))) short short8;
typedef __attribute__((ext_vector_type(4))) float f32x4;

__device__ __forceinline__ float wave_sum(float v) {
#pragma unroll
    for (int off = 32; off > 0; off >>= 1) v += __shfl_xor(v, off, 64);
    return v;
}

__device__ __forceinline__ float fast_rcp(float x) {
    return __builtin_amdgcn_rcpf(x);
}

__device__ __forceinline__ float bcast(float v, int l) {
    return __uint_as_float((unsigned int)__builtin_amdgcn_readlane((int)__float_as_uint(v), l));
}

__device__ __forceinline__ float softplusf(float x) {
    return fmaxf(x, 0.0f) + __logf(1.0f + __expf(-fabsf(x)));
}

__device__ __forceinline__ unsigned short f32_to_bf16(float f) {
    union { float f; unsigned int u; } v; v.f = f;
    unsigned int r = v.u + 0x7fffu + ((v.u >> 16) & 1u);
    return (unsigned short)(r >> 16);
}

// ---------------- Kernel 0: prep — swizzle decoder weights to bf16 frag layout,
// packed phi/theta table, theta logsumexp ----------------
__global__ __launch_bounds__(256) void prep_kernel(
    const float* __restrict__ Wd_mu, const float* __restrict__ Wd_sig,
    const float* __restrict__ phi_mus, const float* __restrict__ phi_sigs,
    const float* __restrict__ theta_mus, const float* __restrict__ theta_sigs,
    const float* __restrict__ theta_logits,
    unsigned short* __restrict__ wmu_s, unsigned short* __restrict__ wsg_s,
    float4* __restrict__ tab4, float* __restrict__ lsetp)
{
    int idx = blockIdx.x * 256 + threadIdx.x;
    if (idx < 65536) {
        int mat = idx >> 15;            // 0: mu, 1: sig
        int e = idx & 32767;
        int j = e & 7;
        int n = (e >> 3) & 15;
        int q = (e >> 7) & 7;
        int tg = e >> 10;
        int k = q * 8 + j;
        int col = tg * 16 + n;
        const float* W = mat ? Wd_sig : Wd_mu;
        unsigned short* o = mat ? wsg_s : wmu_s;
        o[e] = f32_to_bf16(W[k * YD + col]);
    } else if (idx < 65536 + 1024) {
        int e = idx - 65536;
        float4 t;
        t.x = phi_mus[e];
        t.y = phi_sigs[e];
        t.z = theta_mus[e];
        t.w = theta_sigs[e];
        tab4[e] = t;
    } else if (idx == 65536 + 1024) {
        float mt = theta_logits[0];
        for (int k = 1; k < KK; ++k) mt = fmaxf(mt, theta_logits[k]);
        float st = 0.f;
        for (int k = 0; k < KK; ++k) st += __expf(theta_logits[k] - mt);
        lsetp[0] = mt + __logf(st);
    }
}

// ---------------- Kernel 1: encoder GEMM (Y @ We_mu / We_sig) ----------------
__global__ __launch_bounds__(256) void encoder_kernel(
    const float* __restrict__ Y, const float* __restrict__ We_mu,
    const float* __restrict__ be_mu, const float* __restrict__ We_sig,
    const float* __restrict__ be_sig, float* __restrict__ enc_mu,
    float* __restrict__ enc_sig)
{
    __shared__ float Ys[16][YD + 4];
    const int t = threadIdx.x;
    const int n0 = blockIdx.x * 16;

    const float4* Y4 = (const float4*)(Y + (size_t)n0 * YD);
#pragma unroll
    for (int i = 0; i < 8; ++i) {
        int f = t + i * 256;
        int r = f >> 7;
        int c4 = f & 127;
        float4 v = Y4[r * 128 + c4];
        *((float4*)&Ys[r][c4 * 4]) = v;
    }
    __syncthreads();

    const int c4 = (t & 15) * 4;
    const int r = t >> 4;
    float amu[4] = {0.f, 0.f, 0.f, 0.f};
    float asg[4] = {0.f, 0.f, 0.f, 0.f};
    const float* wm = We_mu + c4;
    const float* wsp = We_sig + c4;

#pragma unroll 4
    for (int k = 0; k < YD; ++k) {
        float4 wmu = *(const float4*)(wm + k * XD);
        float4 wsg = *(const float4*)(wsp + k * XD);
        float y = Ys[r][k];
        amu[0] = fmaf(y, wmu.x, amu[0]);
        amu[1] = fmaf(y, wmu.y, amu[1]);
        amu[2] = fmaf(y, wmu.z, amu[2]);
        amu[3] = fmaf(y, wmu.w, amu[3]);
        asg[0] = fmaf(y, wsg.x, asg[0]);
        asg[1] = fmaf(y, wsg.y, asg[1]);
        asg[2] = fmaf(y, wsg.z, asg[2]);
        asg[3] = fmaf(y, wsg.w, asg[3]);
    }

    const int n = n0 + r;
    float4 bm = *(const float4*)(be_mu + c4);
    float4 bs = *(const float4*)(be_sig + c4);
    float4 om, os;
    om.x = amu[0] + bm.x;  om.y = amu[1] + bm.y;
    om.z = amu[2] + bm.z;  om.w = amu[3] + bm.w;
    os.x = softplusf(asg[0] + bs.x) + 1e-3f;
    os.y = softplusf(asg[1] + bs.y) + 1e-3f;
    os.z = softplusf(asg[2] + bs.z) + 1e-3f;
    os.w = softplusf(asg[3] + bs.w) + 1e-3f;
    *(float4*)(enc_mu + (size_t)n * XD + c4) = om;
    *(float4*)(enc_sig + (size_t)n * XD + c4) = os;
}

// ---------------- Kernel 2a: responsibilities (z_log_probs) + loss5 ----------------
__global__ __launch_bounds__(256) void resp_kernel(
    const float* __restrict__ enc_mu_g, const float* __restrict__ enc_sig_g,
    const float* __restrict__ phi_mus, const float* __restrict__ phi_sigs,
    const float* __restrict__ phi_logits,
    float* __restrict__ zlp, double* __restrict__ slotsL5)
{
    __shared__ float red[4];
    const int wv = threadIdx.x >> 6;
    const int n = blockIdx.x * 4 + wv;
    const int d = threadIdx.x & 63;

    const float em = enc_mu_g[(size_t)n * XD + d];
    const float es = enc_sig_g[(size_t)n * XD + d];

    float zl[KK];
#pragma unroll
    for (int k = 0; k < KK; ++k) {
        float sd = es + phi_sigs[k * XD + d];
        float diff = (em - phi_mus[k * XD + d]) * fast_rcp(sd);
        float r = fmaf(-0.5f * diff, diff, -__logf(sd));
        r = wave_sum(r);
        zl[k] = r + phi_logits[k];
    }
    float mx = zl[0];
#pragma unroll
    for (int k = 1; k < KK; ++k) mx = fmaxf(mx, zl[k]);
    float sum = 0.f;
#pragma unroll
    for (int k = 0; k < KK; ++k) sum += __expf(zl[k] - mx);
    float lse = mx + __logf(sum);
#pragma unroll
    for (int k = 0; k < KK; ++k) zl[k] -= lse;

    // loss5 term: log(sum exp(z_log_probs))
    float m3 = zl[0];
#pragma unroll
    for (int k = 1; k < KK; ++k) m3 = fmaxf(m3, zl[k]);
    float s3 = 0.f;
#pragma unroll
    for (int k = 0; k < KK; ++k) s3 += __expf(zl[k] - m3);
    float l5 = m3 + __logf(s3);

    float v = zl[0];
#pragma unroll
    for (int k = 1; k < KK; ++k) v = (d == k) ? zl[k] : v;
    if (d < KK) zlp[(size_t)n * KK + d] = v;

    if (d == 0) red[wv] = l5;
    __syncthreads();
    if (threadIdx.x == 0) {
        float t = red[0] + red[1] + red[2] + red[3];
        atomicAdd(slotsL5 + (blockIdx.x & 63), (double)t);
    }
}

// ---------------- Kernel 2b: gumbel sampling + losses 2/3/4, one wave per (n,s) ----------------
__global__ __launch_bounds__(256, 6) void sample_kernel(
    const float* __restrict__ enc_mu_g, const float* __restrict__ enc_sig_g,
    const float* __restrict__ zlp, const float4* __restrict__ tab4,
    const float* __restrict__ theta_logits, const float* __restrict__ lsetp,
    const float* __restrict__ u_noise, const float* __restrict__ eps_noise,
    const float* __restrict__ temperature,
    unsigned short* __restrict__ x_bf16, double* __restrict__ slots234,
    unsigned int magicS)
{
    __shared__ float red[4];
    const int wv = threadIdx.x >> 6;
    const int wid = blockIdx.x * 4 + wv;   // = n*S + s
    const int d = threadIdx.x & 63;
    const int n = (int)(((unsigned long long)(unsigned int)wid * magicS) >> 35);

    // ---- lane-parallel gumbel + softmax weights (k = d & 15, 4x replicated) ----
    const int kd = d & 15;
    const float invT = fast_rcp(temperature[0]);
    float zlk = zlp[(size_t)n * KK + kd];
    float u   = u_noise[(size_t)wid * KK + kd];
    float tlk = theta_logits[kd];
    float lgk = (zlk - __logf(-__logf(u))) * invT;
    float mg = lgk;
    mg = fmaxf(mg, __shfl_xor(mg, 1, 64));
    mg = fmaxf(mg, __shfl_xor(mg, 2, 64));
    mg = fmaxf(mg, __shfl_xor(mg, 4, 64));
    mg = fmaxf(mg, __shfl_xor(mg, 8, 64));
    float ek = __expf(lgk - mg);
    float zs = ek;
    float pz = ek * zlk;
    float pt = ek * tlk;
#pragma unroll
    for (int off = 1; off <= 8; off <<= 1) {
        zs += __shfl_xor(zs, off, 64);
        pz += __shfl_xor(pz, off, 64);
        pt += __shfl_xor(pt, off, 64);
    }
    const float rn   = fast_rcp(bcast(zs, 0));
    const float dzS  = bcast(pz, 0) * rn;
    const float dthS = bcast(pt, 0) * rn;

    // ---- per-dim mixture accumulation (e_k broadcast from lane k as SGPR) ----
    const float em = enc_mu_g[(size_t)n * XD + d];
    const float es = enc_sig_g[(size_t)n * XD + d];
    const float inv_es = fast_rcp(es);
    const float log_es = __logf(es);
    const float em_ie = inv_es * em;

    float ms = 0.f, Ss = 0.f, tmu = 0.f, tsig = 0.f, pmu = 0.f, psig = 0.f;
#pragma unroll
    for (int k = 0; k < KK; ++k) {
        float e_k = bcast(ek, k);
        float4 tb = tab4[k * XD + d];     // {phi_mu, phi_sig, th_mu, th_sig}
        float ig = fast_rcp(tb.y);
        float Sg = fast_rcp(inv_es + ig);
        float mu = Sg * fmaf(ig, tb.x, em_ie);
        ms   = fmaf(e_k, mu, ms);
        Ss   = fmaf(e_k, Sg, Ss);
        tmu  = fmaf(e_k, tb.z, tmu);
        tsig = fmaf(e_k, tb.w, tsig);
        pmu  = fmaf(e_k, tb.x, pmu);
        psig = fmaf(e_k, tb.y, psig);
    }
    ms *= rn; Ss *= rn; tmu *= rn; tsig *= rn; pmu *= rn; psig *= rn;

    float ep = eps_noise[(size_t)wid * XD + d];
    float x = fmaf(__builtin_amdgcn_sqrtf(Ss), ep, ms);
    x_bf16[(size_t)wid * XD + d] = f32_to_bf16(x);

    float de  = (x - em) * inv_es;
    float dt2 = (x - tmu) * fast_rcp(tsig);
    float dp  = (x - pmu) * fast_rcp(psig);
    float r = 0.5f * (de * de - dt2 * dt2 + dp * dp)
            + log_es - __logf(tsig) + __logf(psig);
    r = wave_sum(r);

    const float C234 = 0.5f * XD * 1.8378770664093453f;
    float acc = r + C234 + (dthS - lsetp[0]) - dzS;

    if (d == 0) red[wv] = acc;
    __syncthreads();
    if (threadIdx.x == 0) {
        float t = red[0] + red[1] + red[2] + red[3];
        atomicAdd(slots234 + (blockIdx.x & 63), (double)t);
    }
}

// ---------------- Kernel 3: decoder via bf16 MFMA + fused loss1 ----------------
__global__ __launch_bounds__(256) void decoder_mfma(
    const unsigned short* __restrict__ xb,
    const unsigned short* __restrict__ wmu_s,
    const unsigned short* __restrict__ wsg_s,
    const float* __restrict__ bd_mu, const float* __restrict__ bd_sig,
    const float* __restrict__ Y, double* __restrict__ slots1,
    unsigned int magicS)
{
    __shared__ float red[4];
    const int t = threadIdx.x;
    const int w = t >> 6;
    const int lane = t & 63;
    const int l16 = lane & 15;
    const int quad = lane >> 4;
    const int mb = blockIdx.x >> 3;
    const int nb = blockIdx.x & 7;

    const int mrow = mb * 64 + w * 16 + l16;
    const short8 a0 = *(const short8*)(xb + (size_t)mrow * XD + quad * 8);
    const short8 a1 = *(const short8*)(xb + (size_t)mrow * XD + 32 + quad * 8);

    f32x4 accmu[4], accsg[4];
#pragma unroll
    for (int tt = 0; tt < 4; ++tt) {
        accmu[tt] = (f32x4){0.f, 0.f, 0.f, 0.f};
        accsg[tt] = (f32x4){0.f, 0.f, 0.f, 0.f};
    }

#pragma unroll
    for (int tt = 0; tt < 4; ++tt) {
        int tg = nb * 4 + tt;
        int boff = ((tg * 8 + quad) * 16 + l16) * 8;
        short8 b0 = *(const short8*)(wmu_s + boff);
        short8 b1 = *(const short8*)(wmu_s + boff + 512);
        short8 c0 = *(const short8*)(wsg_s + boff);
        short8 c1 = *(const short8*)(wsg_s + boff + 512);
        accmu[tt] = __builtin_amdgcn_mfma_f32_16x16x32_bf16(a0, b0, accmu[tt], 0, 0, 0);
        accmu[tt] = __builtin_amdgcn_mfma_f32_16x16x32_bf16(a1, b1, accmu[tt], 0, 0, 0);
        accsg[tt] = __builtin_amdgcn_mfma_f32_16x16x32_bf16(a0, c0, accsg[tt], 0, 0, 0);
        accsg[tt] = __builtin_amdgcn_mfma_f32_16x16x32_bf16(a1, c1, accsg[tt], 0, 0, 0);
    }

    float part = 0.f;
    const int m_base = mb * 64 + w * 16 + quad * 4;
#pragma unroll
    for (int tt = 0; tt < 4; ++tt) {
        int col = (nb * 4 + tt) * 16 + l16;
        float bmv = bd_mu[col], bsv = bd_sig[col];
#pragma unroll
        for (int r = 0; r < 4; ++r) {
            int row = m_base + r;
            unsigned int ny = (unsigned int)(((unsigned long long)(unsigned int)row * magicS) >> 35);
            float Yv = Y[(size_t)ny * YD + col];
            float sig = softplusf(accsg[tt][r] + bsv) + 1e-3f;
            float diff = (Yv - (accmu[tt][r] + bmv)) * fast_rcp(sig);
            part = fmaf(-0.5f * diff, diff, part) - __logf(sig);
        }
    }
    part = wave_sum(part);
    if (lane == 0) red[w] = part;
    __syncthreads();
    if (t == 0) {
        atomicAdd(slots1 + (blockIdx.x & 63),
                  (double)(red[0] + red[1] + red[2] + red[3]));
    }
}

// ---------------- Kernel 4: finalize ----------------
__global__ void finalize_kernel(const double* __restrict__ slots,
                                float* __restrict__ out, int NS, int S)
{
    double l234 = 0.0, l5 = 0.0, l1 = 0.0;
    for (int i = 0; i < 64; ++i) {
        l234 += slots[i];
        l5   += slots[64 + i];
        l1   += slots[128 + i];
    }
    l1 += (double)NS * (-0.5 * (double)YD * 1.8378770664093453);
    out[0] = (float)(-((l1 + l234) / (double)S + l5));
}

extern "C" void kernel_launch(void* const* d_in, const int* in_sizes, int n_in,
                              void* d_out, int out_size, void* d_ws, size_t ws_size,
                              hipStream_t stream) {
    const float* Y            = (const float*)d_in[0];
    const float* We_mu        = (const float*)d_in[1];
    const float* be_mu        = (const float*)d_in[2];
    const float* We_sig       = (const float*)d_in[3];
    const float* be_sig       = (const float*)d_in[4];
    const float* Wd_mu        = (const float*)d_in[5];
    const float* bd_mu        = (const float*)d_in[6];
    const float* Wd_sig       = (const float*)d_in[7];
    const float* bd_sig       = (const float*)d_in[8];
    const float* phi_mus      = (const float*)d_in[9];
    const float* phi_sigs     = (const float*)d_in[10];
    const float* phi_logits   = (const float*)d_in[11];
    const float* theta_mus    = (const float*)d_in[12];
    const float* theta_sigs   = (const float*)d_in[13];
    const float* theta_logits = (const float*)d_in[14];
    const float* u_noise      = (const float*)d_in[15];
    const float* eps_noise    = (const float*)d_in[16];
    const float* temperature  = (const float*)d_in[17];

    const int N = in_sizes[0] / YD;           // 8192
    const int S = in_sizes[15] / (N * KK);    // 10
    const int NS = N * S;
    const unsigned int magicS =
        (unsigned int)((((unsigned long long)1 << 35) + S - 1) / (unsigned long long)S);

    char* base = (char*)d_ws;
    double* slots = (double*)base;                       // 192 doubles (3 x 64)
    float* enc_mu  = (float*)(base + 2048);
    float* enc_sig = enc_mu + (size_t)N * XD;
    float* zlp     = enc_sig + (size_t)N * XD;
    float4* tab4   = (float4*)(zlp + (size_t)N * KK);    // 1024 float4
    float* lsetp   = (float*)(tab4 + 1024);
    unsigned short* xb    = (unsigned short*)(lsetp + 16);
    unsigned short* wmu_s = xb + (size_t)NS * XD;
    unsigned short* wsg_s = wmu_s + 32768;

    hipMemsetAsync(slots, 0, 2048, stream);

    prep_kernel<<<261, 256, 0, stream>>>(Wd_mu, Wd_sig, phi_mus, phi_sigs,
                                         theta_mus, theta_sigs, theta_logits,
                                         wmu_s, wsg_s, tab4, lsetp);
    encoder_kernel<<<N / 16, 256, 0, stream>>>(Y, We_mu, be_mu, We_sig, be_sig,
                                               enc_mu, enc_sig);
    resp_kernel<<<N / 4, 256, 0, stream>>>(enc_mu, enc_sig, phi_mus, phi_sigs,
                                           phi_logits, zlp, slots + 64);
    sample_kernel<<<NS / 4, 256, 0, stream>>>(enc_mu, enc_sig, zlp, tab4,
                                              theta_logits, lsetp,
                                              u_noise, eps_noise, temperature,
                                              xb, slots, magicS);
    decoder_mfma<<<(NS / 64) * (YD / 64), 256, 0, stream>>>(
        xb, wmu_s, wsg_s, bd_mu, bd_sig, Y, slots + 128, magicS);
    finalize_kernel<<<1, 1, 0, stream>>>(slots, (float*)d_out, NS, S);
}

// Round 4
// 240.350 us; speedup vs baseline: 2.3834x; 1.2082x over previous
//
#include <hip/hip_runtime.h>
#include <math.h>

#define YD 512
#define XD 64
#define KK 16

typedef __attribute__((ext_vector_type(8))) short short8;
typedef __attribute__((ext_vector_type(4))) float f32x4;

__device__ __forceinline__ float wave_sum(float v) {
#pragma unroll
    for (int off = 32; off > 0; off >>= 1) v += __shfl_xor(v, off, 64);
    return v;
}

__device__ __forceinline__ float fast_rcp(float x) {
    return __builtin_amdgcn_rcpf(x);
}

__device__ __forceinline__ float bcast(float v, int l) {
    return __uint_as_float((unsigned int)__builtin_amdgcn_readlane((int)__float_as_uint(v), l));
}

__device__ __forceinline__ float softplusf(float x) {
    return fmaxf(x, 0.0f) + __logf(1.0f + __expf(-fabsf(x)));
}

__device__ __forceinline__ unsigned short f32_to_bf16(float f) {
    union { float f; unsigned int u; } v; v.f = f;
    unsigned int r = v.u + 0x7fffu + ((v.u >> 16) & 1u);
    return (unsigned short)(r >> 16);
}

// pack two f32 -> one dword of 2 bf16 (rne), a in [15:0], b in [31:16]
__device__ __forceinline__ unsigned int pack2_bf16(float a, float b) {
    unsigned int ua = __float_as_uint(a), ub = __float_as_uint(b);
    ua = (ua + 0x7fffu + ((ua >> 16) & 1u)) >> 16;
    ub = (ub + 0x7fffu + ((ub >> 16) & 1u)) & 0xffff0000u;
    return ua | ub;
}

// ---------------- Kernel 0: prep ----------------
// idx < 65536            : decoder weight swizzle (as before)
// 65536 <= idx < 131072  : encoder weight swizzle
// 131072 <= idx < 132096 : packed phi/theta table
// idx == 132096          : theta logsumexp
__global__ __launch_bounds__(256) void prep_kernel(
    const float* __restrict__ Wd_mu, const float* __restrict__ Wd_sig,
    const float* __restrict__ We_mu, const float* __restrict__ We_sig,
    const float* __restrict__ phi_mus, const float* __restrict__ phi_sigs,
    const float* __restrict__ theta_mus, const float* __restrict__ theta_sigs,
    const float* __restrict__ theta_logits,
    unsigned short* __restrict__ wmu_s, unsigned short* __restrict__ wsg_s,
    unsigned short* __restrict__ wenc,
    float4* __restrict__ tab4, float* __restrict__ lsetp)
{
    int idx = blockIdx.x * 256 + threadIdx.x;
    if (idx < 65536) {
        int mat = idx >> 15;            // 0: mu, 1: sig
        int e = idx & 32767;
        int j = e & 7;
        int n = (e >> 3) & 15;
        int q = (e >> 7) & 7;
        int tg = e >> 10;
        int k = q * 8 + j;
        int col = tg * 16 + n;
        const float* W = mat ? Wd_sig : Wd_mu;
        unsigned short* o = mat ? wsg_s : wmu_s;
        o[e] = f32_to_bf16(W[k * YD + col]);
    } else if (idx < 131072) {
        int ii = idx - 65536;
        int mat = ii >> 15;             // 0: We_mu, 1: We_sig
        int e = ii & 32767;
        int j = e & 7;
        int n = (e >> 3) & 15;
        int q = (e >> 7) & 3;
        int ct = (e >> 9) & 3;
        int kt = e >> 11;
        int k = kt * 32 + q * 8 + j;    // 0..511
        int col = ct * 16 + n;          // 0..63
        const float* W = mat ? We_sig : We_mu;
        wenc[mat * 32768 + e] = f32_to_bf16(W[k * XD + col]);
    } else if (idx < 131072 + 1024) {
        int e = idx - 131072;
        float4 t;
        t.x = phi_mus[e];
        t.y = phi_sigs[e];
        t.z = theta_mus[e];
        t.w = theta_sigs[e];
        tab4[e] = t;
    } else if (idx == 131072 + 1024) {
        float mt = theta_logits[0];
        for (int k = 1; k < KK; ++k) mt = fmaxf(mt, theta_logits[k]);
        float st = 0.f;
        for (int k = 0; k < KK; ++k) st += __expf(theta_logits[k] - mt);
        lsetp[0] = mt + __logf(st);
    }
}

// ---------------- Kernel 1: encoder via bf16 MFMA ----------------
// grid = (N/32)*2 blocks; block: mat = b&1, 32 rows. 4 waves: wave handles
// 16 rows x 32 cols (2 col-tiles). Y packed to bf16 in-register.
__global__ __launch_bounds__(256) void encoder_mfma(
    const float* __restrict__ Y,
    const unsigned short* __restrict__ wenc,  // [2][32768] swizzled bf16
    const float* __restrict__ be_mu, const float* __restrict__ be_sig,
    float* __restrict__ enc_mu, float* __restrict__ enc_sig)
{
    const int t = threadIdx.x;
    const int w = t >> 6, lane = t & 63, l16 = lane & 15, quad = lane >> 4;
    const int mat = blockIdx.x & 1;
    const int rt = blockIdx.x >> 1;            // 32-row tile
    const int row = rt * 32 + (w >> 1) * 16 + l16;
    const int ct0 = (w & 1) * 2;               // col tiles {ct0, ct0+1}
    const unsigned short* Ws = wenc + mat * 32768;
    const float4* Yrow = (const float4*)(Y + (size_t)row * YD);

    f32x4 acc0 = (f32x4){0.f, 0.f, 0.f, 0.f};
    f32x4 acc1 = (f32x4){0.f, 0.f, 0.f, 0.f};

#pragma unroll
    for (int kt = 0; kt < 16; ++kt) {
        float4 y0 = Yrow[kt * 8 + quad * 2];
        float4 y1 = Yrow[kt * 8 + quad * 2 + 1];
        union { short8 s; unsigned int u[4]; } a;
        a.u[0] = pack2_bf16(y0.x, y0.y);
        a.u[1] = pack2_bf16(y0.z, y0.w);
        a.u[2] = pack2_bf16(y1.x, y1.y);
        a.u[3] = pack2_bf16(y1.z, y1.w);
        short8 b0 = *(const short8*)(Ws + (((kt * 4 + ct0) * 4 + quad) * 16 + l16) * 8);
        short8 b1 = *(const short8*)(Ws + (((kt * 4 + ct0 + 1) * 4 + quad) * 16 + l16) * 8);
        acc0 = __builtin_amdgcn_mfma_f32_16x16x32_bf16(a.s, b0, acc0, 0, 0, 0);
        acc1 = __builtin_amdgcn_mfma_f32_16x16x32_bf16(a.s, b1, acc1, 0, 0, 0);
    }

    const float* bias = mat ? be_sig : be_mu;
    float* outp = mat ? enc_sig : enc_mu;
    const int base_row = rt * 32 + (w >> 1) * 16 + quad * 4;
#pragma unroll
    for (int h = 0; h < 2; ++h) {
        int col = (ct0 + h) * 16 + l16;
        float bv = bias[col];
        f32x4 acc = h ? acc1 : acc0;
#pragma unroll
        for (int r = 0; r < 4; ++r) {
            float v = acc[r] + bv;
            if (mat) v = softplusf(v) + 1e-3f;
            outp[(size_t)(base_row + r) * XD + col] = v;
        }
    }
}

// ---------------- Kernel 2a: responsibilities, (k,d)-parallel ----------------
// wave handles one n; lane = g*16 + kk: partial sum over dims g*16..g*16+15 for
// cluster kk; 2 shuffles reduce over g; k-softmax is lane-parallel in 16-groups.
__global__ __launch_bounds__(256) void resp_kernel(
    const float* __restrict__ enc_mu_g, const float* __restrict__ enc_sig_g,
    const float* __restrict__ phi_mus, const float* __restrict__ phi_sigs,
    const float* __restrict__ phi_logits,
    float* __restrict__ zlp, double* __restrict__ slotsL5)
{
    __shared__ float red[4];
    const int wv = threadIdx.x >> 6;
    const int n = blockIdx.x * 4 + wv;
    const int lane = threadIdx.x & 63;
    const int kk = lane & 15;
    const int g = lane >> 4;

    const float4* em4 = (const float4*)(enc_mu_g + (size_t)n * XD + g * 16);
    const float4* es4 = (const float4*)(enc_sig_g + (size_t)n * XD + g * 16);
    const float4* pm4 = (const float4*)(phi_mus + kk * XD + g * 16);
    const float4* ps4 = (const float4*)(phi_sigs + kk * XD + g * 16);

    float part = 0.f;
#pragma unroll
    for (int q = 0; q < 4; ++q) {
        float4 em = em4[q], es = es4[q], pm = pm4[q], ps = ps4[q];
        {
            float sd = es.x + ps.x; float df = (em.x - pm.x) * fast_rcp(sd);
            part += fmaf(-0.5f * df, df, -__logf(sd));
        }
        {
            float sd = es.y + ps.y; float df = (em.y - pm.y) * fast_rcp(sd);
            part += fmaf(-0.5f * df, df, -__logf(sd));
        }
        {
            float sd = es.z + ps.z; float df = (em.z - pm.z) * fast_rcp(sd);
            part += fmaf(-0.5f * df, df, -__logf(sd));
        }
        {
            float sd = es.w + ps.w; float df = (em.w - pm.w) * fast_rcp(sd);
            part += fmaf(-0.5f * df, df, -__logf(sd));
        }
    }
    // reduce over the 4 g-groups
    part += __shfl_xor(part, 16, 64);
    part += __shfl_xor(part, 32, 64);
    float zl = part + phi_logits[kk];

    // log_softmax over k (within 16-lane groups)
    float m = zl;
#pragma unroll
    for (int off = 1; off <= 8; off <<= 1) m = fmaxf(m, __shfl_xor(m, off, 64));
    float e = __expf(zl - m);
    float s = e;
#pragma unroll
    for (int off = 1; off <= 8; off <<= 1) s += __shfl_xor(s, off, 64);
    zl -= m + __logf(s);

    // loss5 term: log(sum exp(z_log_probs))
    float m3 = zl;
#pragma unroll
    for (int off = 1; off <= 8; off <<= 1) m3 = fmaxf(m3, __shfl_xor(m3, off, 64));
    float e3 = __expf(zl - m3);
    float s3 = e3;
#pragma unroll
    for (int off = 1; off <= 8; off <<= 1) s3 += __shfl_xor(s3, off, 64);
    float l5 = m3 + __logf(s3);

    if (lane < KK) zlp[(size_t)n * KK + lane] = zl;

    if (lane == 0) red[wv] = l5;
    __syncthreads();
    if (threadIdx.x == 0) {
        float tt = red[0] + red[1] + red[2] + red[3];
        atomicAdd(slotsL5 + (blockIdx.x & 63), (double)tt);
    }
}

// ---------------- Kernel 2b: gumbel sampling + losses 2/3/4 ----------------
__global__ __launch_bounds__(256, 6) void sample_kernel(
    const float* __restrict__ enc_mu_g, const float* __restrict__ enc_sig_g,
    const float* __restrict__ zlp, const float4* __restrict__ tab4,
    const float* __restrict__ theta_logits, const float* __restrict__ lsetp,
    const float* __restrict__ u_noise, const float* __restrict__ eps_noise,
    const float* __restrict__ temperature,
    unsigned short* __restrict__ x_bf16, double* __restrict__ slots234,
    unsigned int magicS)
{
    __shared__ float red[4];
    const int wv = threadIdx.x >> 6;
    const int wid = blockIdx.x * 4 + wv;   // = n*S + s
    const int d = threadIdx.x & 63;
    const int n = (int)(((unsigned long long)(unsigned int)wid * magicS) >> 35);

    const int kd = d & 15;
    const float invT = fast_rcp(temperature[0]);
    float zlk = zlp[(size_t)n * KK + kd];
    float u   = u_noise[(size_t)wid * KK + kd];
    float tlk = theta_logits[kd];
    float lgk = (zlk - __logf(-__logf(u))) * invT;
    float mg = lgk;
    mg = fmaxf(mg, __shfl_xor(mg, 1, 64));
    mg = fmaxf(mg, __shfl_xor(mg, 2, 64));
    mg = fmaxf(mg, __shfl_xor(mg, 4, 64));
    mg = fmaxf(mg, __shfl_xor(mg, 8, 64));
    float ek = __expf(lgk - mg);
    float zs = ek;
    float pz = ek * zlk;
    float pt = ek * tlk;
#pragma unroll
    for (int off = 1; off <= 8; off <<= 1) {
        zs += __shfl_xor(zs, off, 64);
        pz += __shfl_xor(pz, off, 64);
        pt += __shfl_xor(pt, off, 64);
    }
    const float rn   = fast_rcp(bcast(zs, 0));
    const float dzS  = bcast(pz, 0) * rn;
    const float dthS = bcast(pt, 0) * rn;

    const float em = enc_mu_g[(size_t)n * XD + d];
    const float es = enc_sig_g[(size_t)n * XD + d];
    const float inv_es = fast_rcp(es);
    const float log_es = __logf(es);
    const float em_ie = inv_es * em;

    float ms = 0.f, Ss = 0.f, tmu = 0.f, tsig = 0.f, pmu = 0.f, psig = 0.f;
#pragma unroll
    for (int k = 0; k < KK; ++k) {
        float e_k = bcast(ek, k);
        float4 tb = tab4[k * XD + d];     // {phi_mu, phi_sig, th_mu, th_sig}
        float ig = fast_rcp(tb.y);
        float Sg = fast_rcp(inv_es + ig);
        float mu = Sg * fmaf(ig, tb.x, em_ie);
        ms   = fmaf(e_k, mu, ms);
        Ss   = fmaf(e_k, Sg, Ss);
        tmu  = fmaf(e_k, tb.z, tmu);
        tsig = fmaf(e_k, tb.w, tsig);
        pmu  = fmaf(e_k, tb.x, pmu);
        psig = fmaf(e_k, tb.y, psig);
    }
    ms *= rn; Ss *= rn; tmu *= rn; tsig *= rn; pmu *= rn; psig *= rn;

    float ep = eps_noise[(size_t)wid * XD + d];
    float x = fmaf(__builtin_amdgcn_sqrtf(Ss), ep, ms);
    x_bf16[(size_t)wid * XD + d] = f32_to_bf16(x);

    float de  = (x - em) * inv_es;
    float dt2 = (x - tmu) * fast_rcp(tsig);
    float dp  = (x - pmu) * fast_rcp(psig);
    float r = 0.5f * (de * de - dt2 * dt2 + dp * dp)
            + log_es - __logf(tsig) + __logf(psig);
    r = wave_sum(r);

    const float C234 = 0.5f * XD * 1.8378770664093453f;
    float acc = r + C234 + (dthS - lsetp[0]) - dzS;

    if (d == 0) red[wv] = acc;
    __syncthreads();
    if (threadIdx.x == 0) {
        float t = red[0] + red[1] + red[2] + red[3];
        atomicAdd(slots234 + (blockIdx.x & 63), (double)t);
    }
}

// ---------------- Kernel 3: decoder via bf16 MFMA + fused loss1 ----------------
__global__ __launch_bounds__(256) void decoder_mfma(
    const unsigned short* __restrict__ xb,
    const unsigned short* __restrict__ wmu_s,
    const unsigned short* __restrict__ wsg_s,
    const float* __restrict__ bd_mu, const float* __restrict__ bd_sig,
    const float* __restrict__ Y, double* __restrict__ slots1,
    unsigned int magicS)
{
    __shared__ float red[4];
    const int t = threadIdx.x;
    const int w = t >> 6;
    const int lane = t & 63;
    const int l16 = lane & 15;
    const int quad = lane >> 4;
    const int mb = blockIdx.x >> 3;
    const int nb = blockIdx.x & 7;

    const int mrow = mb * 64 + w * 16 + l16;
    const short8 a0 = *(const short8*)(xb + (size_t)mrow * XD + quad * 8);
    const short8 a1 = *(const short8*)(xb + (size_t)mrow * XD + 32 + quad * 8);

    f32x4 accmu[4], accsg[4];
#pragma unroll
    for (int tt = 0; tt < 4; ++tt) {
        accmu[tt] = (f32x4){0.f, 0.f, 0.f, 0.f};
        accsg[tt] = (f32x4){0.f, 0.f, 0.f, 0.f};
    }

#pragma unroll
    for (int tt = 0; tt < 4; ++tt) {
        int tg = nb * 4 + tt;
        int boff = ((tg * 8 + quad) * 16 + l16) * 8;
        short8 b0 = *(const short8*)(wmu_s + boff);
        short8 b1 = *(const short8*)(wmu_s + boff + 512);
        short8 c0 = *(const short8*)(wsg_s + boff);
        short8 c1 = *(const short8*)(wsg_s + boff + 512);
        accmu[tt] = __builtin_amdgcn_mfma_f32_16x16x32_bf16(a0, b0, accmu[tt], 0, 0, 0);
        accmu[tt] = __builtin_amdgcn_mfma_f32_16x16x32_bf16(a1, b1, accmu[tt], 0, 0, 0);
        accsg[tt] = __builtin_amdgcn_mfma_f32_16x16x32_bf16(a0, c0, accsg[tt], 0, 0, 0);
        accsg[tt] = __builtin_amdgcn_mfma_f32_16x16x32_bf16(a1, c1, accsg[tt], 0, 0, 0);
    }

    float part = 0.f;
    const int m_base = mb * 64 + w * 16 + quad * 4;
#pragma unroll
    for (int tt = 0; tt < 4; ++tt) {
        int col = (nb * 4 + tt) * 16 + l16;
        float bmv = bd_mu[col], bsv = bd_sig[col];
#pragma unroll
        for (int r = 0; r < 4; ++r) {
            int row = m_base + r;
            unsigned int ny = (unsigned int)(((unsigned long long)(unsigned int)row * magicS) >> 35);
            float Yv = Y[(size_t)ny * YD + col];
            float sig = softplusf(accsg[tt][r] + bsv) + 1e-3f;
            float diff = (Yv - (accmu[tt][r] + bmv)) * fast_rcp(sig);
            part = fmaf(-0.5f * diff, diff, part) - __logf(sig);
        }
    }
    part = wave_sum(part);
    if (lane == 0) red[w] = part;
    __syncthreads();
    if (t == 0) {
        atomicAdd(slots1 + (blockIdx.x & 63),
                  (double)(red[0] + red[1] + red[2] + red[3]));
    }
}

// ---------------- Kernel 4: finalize ----------------
__global__ void finalize_kernel(const double* __restrict__ slots,
                                float* __restrict__ out, int NS, int S)
{
    double l234 = 0.0, l5 = 0.0, l1 = 0.0;
    for (int i = 0; i < 64; ++i) {
        l234 += slots[i];
        l5   += slots[64 + i];
        l1   += slots[128 + i];
    }
    l1 += (double)NS * (-0.5 * (double)YD * 1.8378770664093453);
    out[0] = (float)(-((l1 + l234) / (double)S + l5));
}

extern "C" void kernel_launch(void* const* d_in, const int* in_sizes, int n_in,
                              void* d_out, int out_size, void* d_ws, size_t ws_size,
                              hipStream_t stream) {
    const float* Y            = (const float*)d_in[0];
    const float* We_mu        = (const float*)d_in[1];
    const float* be_mu        = (const float*)d_in[2];
    const float* We_sig       = (const float*)d_in[3];
    const float* be_sig       = (const float*)d_in[4];
    const float* Wd_mu        = (const float*)d_in[5];
    const float* bd_mu        = (const float*)d_in[6];
    const float* Wd_sig       = (const float*)d_in[7];
    const float* bd_sig       = (const float*)d_in[8];
    const float* phi_mus      = (const float*)d_in[9];
    const float* phi_sigs     = (const float*)d_in[10];
    const float* phi_logits   = (const float*)d_in[11];
    const float* theta_mus    = (const float*)d_in[12];
    const float* theta_sigs   = (const float*)d_in[13];
    const float* theta_logits = (const float*)d_in[14];
    const float* u_noise      = (const float*)d_in[15];
    const float* eps_noise    = (const float*)d_in[16];
    const float* temperature  = (const float*)d_in[17];

    const int N = in_sizes[0] / YD;           // 8192
    const int S = in_sizes[15] / (N * KK);    // 10
    const int NS = N * S;
    const unsigned int magicS =
        (unsigned int)((((unsigned long long)1 << 35) + S - 1) / (unsigned long long)S);

    char* base = (char*)d_ws;
    double* slots = (double*)base;                       // 192 doubles (3 x 64)
    float* enc_mu  = (float*)(base + 2048);
    float* enc_sig = enc_mu + (size_t)N * XD;
    float* zlp     = enc_sig + (size_t)N * XD;
    float4* tab4   = (float4*)(zlp + (size_t)N * KK);    // 1024 float4
    float* lsetp   = (float*)(tab4 + 1024);
    unsigned short* xb    = (unsigned short*)(lsetp + 16);
    unsigned short* wmu_s = xb + (size_t)NS * XD;
    unsigned short* wsg_s = wmu_s + 32768;
    unsigned short* wenc  = wsg_s + 32768;               // 2 x 32768

    hipMemsetAsync(slots, 0, 2048, stream);

    prep_kernel<<<517, 256, 0, stream>>>(Wd_mu, Wd_sig, We_mu, We_sig,
                                         phi_mus, phi_sigs, theta_mus,
                                         theta_sigs, theta_logits,
                                         wmu_s, wsg_s, wenc, tab4, lsetp);
    encoder_mfma<<<(N / 32) * 2, 256, 0, stream>>>(Y, wenc, be_mu, be_sig,
                                                   enc_mu, enc_sig);
    resp_kernel<<<N / 4, 256, 0, stream>>>(enc_mu, enc_sig, phi_mus, phi_sigs,
                                           phi_logits, zlp, slots + 64);
    sample_kernel<<<NS / 4, 256, 0, stream>>>(enc_mu, enc_sig, zlp, tab4,
                                              theta_logits, lsetp,
                                              u_noise, eps_noise, temperature,
                                              xb, slots, magicS);
    decoder_mfma<<<(NS / 64) * (YD / 64), 256, 0, stream>>>(
        xb, wmu_s, wsg_s, bd_mu, bd_sig, Y, slots + 128, magicS);
    finalize_kernel<<<1, 1, 0, stream>>>(slots, (float*)d_out, NS, S);
}

// Round 5
// 220.310 us; speedup vs baseline: 2.6001x; 1.0910x over previous
//
#include <hip/hip_runtime.h>
#include <math.h>

#define YD 512
#define XD 64
#define KK 16
#define SS 10

typedef __attribute__((ext_vector_type(8))) short short8;
typedef __attribute__((ext_vector_type(4))) float f32x4;

__device__ __forceinline__ float wave_sum(float v) {
#pragma unroll
    for (int off = 32; off > 0; off >>= 1) v += __shfl_xor(v, off, 64);
    return v;
}

__device__ __forceinline__ float fast_rcp(float x) {
    return __builtin_amdgcn_rcpf(x);
}

__device__ __forceinline__ float bcast(float v, int l) {
    return __uint_as_float((unsigned int)__builtin_amdgcn_readlane((int)__float_as_uint(v), l));
}

__device__ __forceinline__ float softplusf(float x) {
    return fmaxf(x, 0.0f) + __logf(1.0f + __expf(-fabsf(x)));
}

__device__ __forceinline__ unsigned short f32_to_bf16(float f) {
    union { float f; unsigned int u; } v; v.f = f;
    unsigned int r = v.u + 0x7fffu + ((v.u >> 16) & 1u);
    return (unsigned short)(r >> 16);
}

__device__ __forceinline__ unsigned int pack2_bf16(float a, float b) {
    unsigned int ua = __float_as_uint(a), ub = __float_as_uint(b);
    ua = (ua + 0x7fffu + ((ua >> 16) & 1u)) >> 16;
    ub = (ub + 0x7fffu + ((ub >> 16) & 1u)) & 0xffff0000u;
    return ua | ub;
}

// ---------------- Kernel 0: prep ----------------
__global__ __launch_bounds__(256) void prep_kernel(
    const float* __restrict__ Wd_mu, const float* __restrict__ Wd_sig,
    const float* __restrict__ We_mu, const float* __restrict__ We_sig,
    const float* __restrict__ phi_mus, const float* __restrict__ phi_sigs,
    const float* __restrict__ theta_mus, const float* __restrict__ theta_sigs,
    const float* __restrict__ theta_logits,
    unsigned short* __restrict__ wmu_s, unsigned short* __restrict__ wsg_s,
    unsigned short* __restrict__ wenc,
    float4* __restrict__ tab4, float* __restrict__ lsetp)
{
    int idx = blockIdx.x * 256 + threadIdx.x;
    if (idx < 65536) {
        int mat = idx >> 15;            // 0: mu, 1: sig
        int e = idx & 32767;
        int j = e & 7;
        int n = (e >> 3) & 15;
        int q = (e >> 7) & 7;
        int tg = e >> 10;
        int k = q * 8 + j;
        int col = tg * 16 + n;
        const float* W = mat ? Wd_sig : Wd_mu;
        unsigned short* o = mat ? wsg_s : wmu_s;
        o[e] = f32_to_bf16(W[k * YD + col]);
    } else if (idx < 131072) {
        int ii = idx - 65536;
        int mat = ii >> 15;             // 0: We_mu, 1: We_sig
        int e = ii & 32767;
        int j = e & 7;
        int n = (e >> 3) & 15;
        int q = (e >> 7) & 3;
        int ct = (e >> 9) & 3;
        int kt = e >> 11;
        int k = kt * 32 + q * 8 + j;    // 0..511
        int col = ct * 16 + n;          // 0..63
        const float* W = mat ? We_sig : We_mu;
        wenc[mat * 32768 + e] = f32_to_bf16(W[k * XD + col]);
    } else if (idx < 131072 + 1024) {
        int e = idx - 131072;
        float4 t;
        t.x = phi_mus[e];
        t.y = phi_sigs[e];
        t.z = theta_mus[e];
        t.w = theta_sigs[e];
        tab4[e] = t;
    } else if (idx == 131072 + 1024) {
        float mt = theta_logits[0];
        for (int k = 1; k < KK; ++k) mt = fmaxf(mt, theta_logits[k]);
        float st = 0.f;
        for (int k = 0; k < KK; ++k) st += __expf(theta_logits[k] - mt);
        lsetp[0] = mt + __logf(st);
    }
}

// ---------------- Kernel 1: encoder via bf16 MFMA ----------------
// grid = (N/16)*2; block handles 16 rows of one mat; wave w = col-tile w.
__global__ __launch_bounds__(256) void encoder_mfma(
    const float* __restrict__ Y,
    const unsigned short* __restrict__ wenc,  // [2][32768] swizzled bf16
    const float* __restrict__ be_mu, const float* __restrict__ be_sig,
    float* __restrict__ enc_mu, float* __restrict__ enc_sig)
{
    const int t = threadIdx.x;
    const int w = t >> 6, lane = t & 63, l16 = lane & 15, quad = lane >> 4;
    const int mat = blockIdx.x & 1;
    const int rt = blockIdx.x >> 1;            // 16-row tile
    const int row = rt * 16 + l16;
    const int ct = w;                          // col tile 0..3
    const unsigned short* Ws = wenc + mat * 32768;
    const float4* Yrow = (const float4*)(Y + (size_t)row * YD);

    const float* bias = mat ? be_sig : be_mu;
    float* outp = mat ? enc_sig : enc_mu;
    const int col = ct * 16 + l16;
    const float bv = bias[col];
    f32x4 acc = (f32x4){bv, bv, bv, bv};

#pragma unroll
    for (int kt = 0; kt < 16; ++kt) {
        float4 y0 = Yrow[kt * 8 + quad * 2];
        float4 y1 = Yrow[kt * 8 + quad * 2 + 1];
        union { short8 s; unsigned int u[4]; } a;
        a.u[0] = pack2_bf16(y0.x, y0.y);
        a.u[1] = pack2_bf16(y0.z, y0.w);
        a.u[2] = pack2_bf16(y1.x, y1.y);
        a.u[3] = pack2_bf16(y1.z, y1.w);
        short8 b = *(const short8*)(Ws + (((kt * 4 + ct) * 4 + quad) * 16 + l16) * 8);
        acc = __builtin_amdgcn_mfma_f32_16x16x32_bf16(a.s, b, acc, 0, 0, 0);
    }

    const int base_row = rt * 16 + quad * 4;
#pragma unroll
    for (int r = 0; r < 4; ++r) {
        float v = acc[r];
        if (mat) v = softplusf(v) + 1e-3f;
        outp[(size_t)(base_row + r) * XD + col] = v;
    }
}

// ---------------- Kernel 2a: responsibilities, (k,d)-parallel ----------------
__global__ __launch_bounds__(256) void resp_kernel(
    const float* __restrict__ enc_mu_g, const float* __restrict__ enc_sig_g,
    const float* __restrict__ phi_mus, const float* __restrict__ phi_sigs,
    const float* __restrict__ phi_logits,
    float* __restrict__ zlp, double* __restrict__ slotsL5)
{
    __shared__ float red[4];
    const int wv = threadIdx.x >> 6;
    const int n = blockIdx.x * 4 + wv;
    const int lane = threadIdx.x & 63;
    const int kk = lane & 15;
    const int g = lane >> 4;

    const float4* em4 = (const float4*)(enc_mu_g + (size_t)n * XD + g * 16);
    const float4* es4 = (const float4*)(enc_sig_g + (size_t)n * XD + g * 16);
    const float4* pm4 = (const float4*)(phi_mus + kk * XD + g * 16);
    const float4* ps4 = (const float4*)(phi_sigs + kk * XD + g * 16);

    float part = 0.f;
#pragma unroll
    for (int q = 0; q < 4; ++q) {
        float4 em = em4[q], es = es4[q], pm = pm4[q], ps = ps4[q];
        {
            float sd = es.x + ps.x; float df = (em.x - pm.x) * fast_rcp(sd);
            part += fmaf(-0.5f * df, df, -__logf(sd));
        }
        {
            float sd = es.y + ps.y; float df = (em.y - pm.y) * fast_rcp(sd);
            part += fmaf(-0.5f * df, df, -__logf(sd));
        }
        {
            float sd = es.z + ps.z; float df = (em.z - pm.z) * fast_rcp(sd);
            part += fmaf(-0.5f * df, df, -__logf(sd));
        }
        {
            float sd = es.w + ps.w; float df = (em.w - pm.w) * fast_rcp(sd);
            part += fmaf(-0.5f * df, df, -__logf(sd));
        }
    }
    part += __shfl_xor(part, 16, 64);
    part += __shfl_xor(part, 32, 64);
    float zl = part + phi_logits[kk];

    float m = zl;
#pragma unroll
    for (int off = 1; off <= 8; off <<= 1) m = fmaxf(m, __shfl_xor(m, off, 64));
    float e = __expf(zl - m);
    float s = e;
#pragma unroll
    for (int off = 1; off <= 8; off <<= 1) s += __shfl_xor(s, off, 64);
    zl -= m + __logf(s);

    float m3 = zl;
#pragma unroll
    for (int off = 1; off <= 8; off <<= 1) m3 = fmaxf(m3, __shfl_xor(m3, off, 64));
    float e3 = __expf(zl - m3);
    float s3 = e3;
#pragma unroll
    for (int off = 1; off <= 8; off <<= 1) s3 += __shfl_xor(s3, off, 64);
    float l5 = m3 + __logf(s3);

    if (lane < KK) zlp[(size_t)n * KK + lane] = zl;

    if (lane == 0) red[wv] = l5;
    __syncthreads();
    if (threadIdx.x == 0) {
        float tt = red[0] + red[1] + red[2] + red[3];
        atomicAdd(slotsL5 + (blockIdx.x & 63), (double)tt);
    }
}

// ---------------- Kernel 2b: sampling + losses 2/3/4 — one wave per n ----------------
__global__ __launch_bounds__(256, 3) void sample_kernel(
    const float* __restrict__ enc_mu_g, const float* __restrict__ enc_sig_g,
    const float* __restrict__ zlp, const float4* __restrict__ tab4,
    const float* __restrict__ theta_logits, const float* __restrict__ lsetp,
    const float* __restrict__ u_noise, const float* __restrict__ eps_noise,
    const float* __restrict__ temperature,
    unsigned short* __restrict__ x_bf16, double* __restrict__ slots234)
{
    __shared__ float red[4];
    const int wv = threadIdx.x >> 6;
    const int n = blockIdx.x * 4 + wv;
    const int d = threadIdx.x & 63;
    const int kd = d & 15;

    const float invT = fast_rcp(temperature[0]);
    const float zl_l = zlp[(size_t)n * KK + kd];
    const float tl_l = theta_logits[kd];
    const float lset = lsetp[0];

    const float em = enc_mu_g[(size_t)n * XD + d];
    const float es = enc_sig_g[(size_t)n * XD + d];
    const float inv_es = fast_rcp(es);
    const float log_es = __logf(es);
    const float em_ie = inv_es * em;

    // per-n tables and posterior, held in VGPRs
    float mu[KK], Sg[KK], tm[KK], ts[KK], pm[KK], ps[KK];
#pragma unroll
    for (int k = 0; k < KK; ++k) {
        float4 tb = tab4[k * XD + d];     // {phi_mu, phi_sig, th_mu, th_sig}
        pm[k] = tb.x; ps[k] = tb.y; tm[k] = tb.z; ts[k] = tb.w;
        float ig = fast_rcp(tb.y);
        Sg[k] = fast_rcp(inv_es + ig);
        mu[k] = Sg[k] * fmaf(ig, tb.x, em_ie);
    }

    // gumbel: 4 samples per pass; lane = (sgrp = d>>4, k = d&15)
    float eP[3], dzP[3], dthP[3];
#pragma unroll
    for (int p = 0; p < 3; ++p) {
        int sp = p * 4 + (d >> 4);
        int spc = sp < SS ? sp : 0;       // clamp (results unused)
        float u = u_noise[((size_t)n * SS + spc) * KK + kd];
        float lg = (zl_l - __logf(-__logf(u))) * invT;
        float mg = lg;
        mg = fmaxf(mg, __shfl_xor(mg, 1, 64));
        mg = fmaxf(mg, __shfl_xor(mg, 2, 64));
        mg = fmaxf(mg, __shfl_xor(mg, 4, 64));
        mg = fmaxf(mg, __shfl_xor(mg, 8, 64));
        float e = __expf(lg - mg);
        float zs = e;
        zs += __shfl_xor(zs, 1, 64);
        zs += __shfl_xor(zs, 2, 64);
        zs += __shfl_xor(zs, 4, 64);
        zs += __shfl_xor(zs, 8, 64);
        e *= fast_rcp(zs);                 // normalized weight
        float pz = e * zl_l, pt = e * tl_l;
#pragma unroll
        for (int off = 1; off <= 8; off <<= 1) {
            pz += __shfl_xor(pz, off, 64);
            pt += __shfl_xor(pt, off, 64);
        }
        eP[p] = e; dzP[p] = pz; dthP[p] = pt;
    }

    float r_acc = 0.f, sc_acc = 0.f;
    const float* erow = eps_noise + (size_t)n * SS * XD + d;
    unsigned short* xrow = x_bf16 + (size_t)n * SS * XD + d;

#pragma unroll
    for (int s = 0; s < SS; ++s) {
        const int p = s >> 2, L = (s & 3) * 16;
        float ms = 0.f, Ssum = 0.f, tmu = 0.f, tsig = 0.f, pmu = 0.f, psig = 0.f;
#pragma unroll
        for (int k = 0; k < KK; ++k) {
            float ek = bcast(eP[p], L + k);
            ms   = fmaf(ek, mu[k], ms);
            Ssum = fmaf(ek, Sg[k], Ssum);
            tmu  = fmaf(ek, tm[k], tmu);
            tsig = fmaf(ek, ts[k], tsig);
            pmu  = fmaf(ek, pm[k], pmu);
            psig = fmaf(ek, ps[k], psig);
        }
        float ep = erow[s * XD];
        float x = fmaf(__builtin_amdgcn_sqrtf(Ssum), ep, ms);
        xrow[s * XD] = f32_to_bf16(x);

        float de  = (x - em) * inv_es;
        float rts = fast_rcp(tsig);
        float dt2 = (x - tmu) * rts;
        float dp  = (x - pmu) * fast_rcp(psig);
        r_acc += 0.5f * (de * de - dt2 * dt2 + dp * dp) + __logf(psig * rts);
        sc_acc += bcast(dthP[p], L) - bcast(dzP[p], L);
    }

    r_acc = fmaf((float)SS, log_es, r_acc);
    r_acc = wave_sum(r_acc);

    const float C234 = 0.5f * XD * 1.8378770664093453f;
    float total = r_acc + sc_acc + (float)SS * (C234 - lset);

    if (d == 0) red[wv] = total;
    __syncthreads();
    if (threadIdx.x == 0) {
        float t = red[0] + red[1] + red[2] + red[3];
        atomicAdd(slots234 + (blockIdx.x & 63), (double)t);
    }
}

// ---------------- Kernel 3: decoder via bf16 MFMA + fused loss1 ----------------
__global__ __launch_bounds__(256) void decoder_mfma(
    const unsigned short* __restrict__ xb,
    const unsigned short* __restrict__ wmu_s,
    const unsigned short* __restrict__ wsg_s,
    const float* __restrict__ bd_mu, const float* __restrict__ bd_sig,
    const float* __restrict__ Y, double* __restrict__ slots1,
    unsigned int magicS)
{
    __shared__ float red[4];
    const int t = threadIdx.x;
    const int w = t >> 6;
    const int lane = t & 63;
    const int l16 = lane & 15;
    const int quad = lane >> 4;
    const int mb = blockIdx.x >> 3;
    const int nb = blockIdx.x & 7;

    const int mrow = mb * 64 + w * 16 + l16;
    const short8 a0 = *(const short8*)(xb + (size_t)mrow * XD + quad * 8);
    const short8 a1 = *(const short8*)(xb + (size_t)mrow * XD + 32 + quad * 8);

    f32x4 accmu[4], accsg[4];
#pragma unroll
    for (int tt = 0; tt < 4; ++tt) {
        int col = (nb * 4 + tt) * 16 + l16;
        float bm = bd_mu[col], bs = bd_sig[col];
        accmu[tt] = (f32x4){bm, bm, bm, bm};
        accsg[tt] = (f32x4){bs, bs, bs, bs};
    }

#pragma unroll
    for (int tt = 0; tt < 4; ++tt) {
        int tg = nb * 4 + tt;
        int boff = ((tg * 8 + quad) * 16 + l16) * 8;
        short8 b0 = *(const short8*)(wmu_s + boff);
        short8 b1 = *(const short8*)(wmu_s + boff + 512);
        short8 c0 = *(const short8*)(wsg_s + boff);
        short8 c1 = *(const short8*)(wsg_s + boff + 512);
        accmu[tt] = __builtin_amdgcn_mfma_f32_16x16x32_bf16(a0, b0, accmu[tt], 0, 0, 0);
        accmu[tt] = __builtin_amdgcn_mfma_f32_16x16x32_bf16(a1, b1, accmu[tt], 0, 0, 0);
        accsg[tt] = __builtin_amdgcn_mfma_f32_16x16x32_bf16(a0, c0, accsg[tt], 0, 0, 0);
        accsg[tt] = __builtin_amdgcn_mfma_f32_16x16x32_bf16(a1, c1, accsg[tt], 0, 0, 0);
    }

    float part = 0.f;
    const int m_base = mb * 64 + w * 16 + quad * 4;
#pragma unroll
    for (int r = 0; r < 4; ++r) {
        int row = m_base + r;
        unsigned int ny = (unsigned int)(((unsigned long long)(unsigned int)row * magicS) >> 35);
        const float* Yr = Y + (size_t)ny * YD + l16;
#pragma unroll
        for (int tt = 0; tt < 4; ++tt) {
            float Yv = Yr[(nb * 4 + tt) * 16];
            float sig = softplusf(accsg[tt][r]) + 1e-3f;
            float diff = (Yv - accmu[tt][r]) * fast_rcp(sig);
            part = fmaf(-0.5f * diff, diff, part) - __logf(sig);
        }
    }
    part = wave_sum(part);
    if (lane == 0) red[w] = part;
    __syncthreads();
    if (t == 0) {
        atomicAdd(slots1 + (blockIdx.x & 63),
                  (double)(red[0] + red[1] + red[2] + red[3]));
    }
}

// ---------------- Kernel 4: finalize ----------------
__global__ void finalize_kernel(const double* __restrict__ slots,
                                float* __restrict__ out, int NS, int S)
{
    double l234 = 0.0, l5 = 0.0, l1 = 0.0;
    for (int i = 0; i < 64; ++i) {
        l234 += slots[i];
        l5   += slots[64 + i];
        l1   += slots[128 + i];
    }
    l1 += (double)NS * (-0.5 * (double)YD * 1.8378770664093453);
    out[0] = (float)(-((l1 + l234) / (double)S + l5));
}

extern "C" void kernel_launch(void* const* d_in, const int* in_sizes, int n_in,
                              void* d_out, int out_size, void* d_ws, size_t ws_size,
                              hipStream_t stream) {
    const float* Y            = (const float*)d_in[0];
    const float* We_mu        = (const float*)d_in[1];
    const float* be_mu        = (const float*)d_in[2];
    const float* We_sig       = (const float*)d_in[3];
    const float* be_sig       = (const float*)d_in[4];
    const float* Wd_mu        = (const float*)d_in[5];
    const float* bd_mu        = (const float*)d_in[6];
    const float* Wd_sig       = (const float*)d_in[7];
    const float* bd_sig       = (const float*)d_in[8];
    const float* phi_mus      = (const float*)d_in[9];
    const float* phi_sigs     = (const float*)d_in[10];
    const float* phi_logits   = (const float*)d_in[11];
    const float* theta_mus    = (const float*)d_in[12];
    const float* theta_sigs   = (const float*)d_in[13];
    const float* theta_logits = (const float*)d_in[14];
    const float* u_noise      = (const float*)d_in[15];
    const float* eps_noise    = (const float*)d_in[16];
    const float* temperature  = (const float*)d_in[17];

    const int N = in_sizes[0] / YD;           // 8192
    const int S = in_sizes[15] / (N * KK);    // 10 (== SS)
    const int NS = N * S;
    const unsigned int magicS =
        (unsigned int)((((unsigned long long)1 << 35) + S - 1) / (unsigned long long)S);

    char* base = (char*)d_ws;
    double* slots = (double*)base;                       // 192 doubles (3 x 64)
    float* enc_mu  = (float*)(base + 2048);
    float* enc_sig = enc_mu + (size_t)N * XD;
    float* zlp     = enc_sig + (size_t)N * XD;
    float4* tab4   = (float4*)(zlp + (size_t)N * KK);    // 1024 float4
    float* lsetp   = (float*)(tab4 + 1024);
    unsigned short* xb    = (unsigned short*)(lsetp + 16);
    unsigned short* wmu_s = xb + (size_t)NS * XD;
    unsigned short* wsg_s = wmu_s + 32768;
    unsigned short* wenc  = wsg_s + 32768;               // 2 x 32768

    hipMemsetAsync(slots, 0, 2048, stream);

    prep_kernel<<<517, 256, 0, stream>>>(Wd_mu, Wd_sig, We_mu, We_sig,
                                         phi_mus, phi_sigs, theta_mus,
                                         theta_sigs, theta_logits,
                                         wmu_s, wsg_s, wenc, tab4, lsetp);
    encoder_mfma<<<(N / 16) * 2, 256, 0, stream>>>(Y, wenc, be_mu, be_sig,
                                                   enc_mu, enc_sig);
    resp_kernel<<<N / 4, 256, 0, stream>>>(enc_mu, enc_sig, phi_mus, phi_sigs,
                                           phi_logits, zlp, slots + 64);
    sample_kernel<<<N / 4, 256, 0, stream>>>(enc_mu, enc_sig, zlp, tab4,
                                             theta_logits, lsetp,
                                             u_noise, eps_noise, temperature,
                                             xb, slots);
    decoder_mfma<<<(NS / 64) * (YD / 64), 256, 0, stream>>>(
        xb, wmu_s, wsg_s, bd_mu, bd_sig, Y, slots + 128, magicS);
    finalize_kernel<<<1, 1, 0, stream>>>(slots, (float*)d_out, NS, S);
}

// Round 6
// 208.964 us; speedup vs baseline: 2.7413x; 1.0543x over previous
//
#include <hip/hip_runtime.h>
#include <math.h>

#define YD 512
#define XD 64
#define KK 16
#define SS 10

typedef __attribute__((ext_vector_type(8))) short short8;
typedef __attribute__((ext_vector_type(4))) float f32x4;

__device__ __forceinline__ float wave_sum(float v) {
#pragma unroll
    for (int off = 32; off > 0; off >>= 1) v += __shfl_xor(v, off, 64);
    return v;
}

__device__ __forceinline__ float fast_rcp(float x) {
    return __builtin_amdgcn_rcpf(x);
}

__device__ __forceinline__ float bcast(float v, int l) {
    return __uint_as_float((unsigned int)__builtin_amdgcn_readlane((int)__float_as_uint(v), l));
}

__device__ __forceinline__ float softplusf(float x) {
    return fmaxf(x, 0.0f) + __logf(1.0f + __expf(-fabsf(x)));
}

__device__ __forceinline__ unsigned short f32_to_bf16(float f) {
    union { float f; unsigned int u; } v; v.f = f;
    unsigned int r = v.u + 0x7fffu + ((v.u >> 16) & 1u);
    return (unsigned short)(r >> 16);
}

__device__ __forceinline__ unsigned int pack2_bf16(float a, float b) {
    unsigned int ua = __float_as_uint(a), ub = __float_as_uint(b);
    ua = (ua + 0x7fffu + ((ua >> 16) & 1u)) >> 16;
    ub = (ub + 0x7fffu + ((ub >> 16) & 1u)) & 0xffff0000u;
    return ua | ub;
}

// ---------------- Kernel 0: prep ----------------
__global__ __launch_bounds__(256) void prep_kernel(
    const float* __restrict__ Wd_mu, const float* __restrict__ Wd_sig,
    const float* __restrict__ We_mu, const float* __restrict__ We_sig,
    const float* __restrict__ phi_mus, const float* __restrict__ phi_sigs,
    const float* __restrict__ theta_mus, const float* __restrict__ theta_sigs,
    const float* __restrict__ theta_logits,
    unsigned short* __restrict__ wmu_s, unsigned short* __restrict__ wsg_s,
    unsigned short* __restrict__ wenc,
    float4* __restrict__ tab4, float* __restrict__ lsetp)
{
    int idx = blockIdx.x * 256 + threadIdx.x;
    if (idx < 65536) {
        int mat = idx >> 15;            // 0: mu, 1: sig
        int e = idx & 32767;
        int j = e & 7;
        int n = (e >> 3) & 15;
        int q = (e >> 7) & 7;
        int tg = e >> 10;
        int k = q * 8 + j;
        int col = tg * 16 + n;
        const float* W = mat ? Wd_sig : Wd_mu;
        unsigned short* o = mat ? wsg_s : wmu_s;
        o[e] = f32_to_bf16(W[k * YD + col]);
    } else if (idx < 131072) {
        int ii = idx - 65536;
        int mat = ii >> 15;             // 0: We_mu, 1: We_sig
        int e = ii & 32767;
        int j = e & 7;
        int n = (e >> 3) & 15;
        int q = (e >> 7) & 3;
        int ct = (e >> 9) & 3;
        int kt = e >> 11;
        int k = kt * 32 + q * 8 + j;    // 0..511
        int col = ct * 16 + n;          // 0..63
        const float* W = mat ? We_sig : We_mu;
        wenc[mat * 32768 + e] = f32_to_bf16(W[k * XD + col]);
    } else if (idx < 131072 + 1024) {
        int e = idx - 131072;
        float4 t;
        t.x = phi_mus[e];
        t.y = phi_sigs[e];
        t.z = theta_mus[e];
        t.w = theta_sigs[e];
        tab4[e] = t;
    } else if (idx == 131072 + 1024) {
        float mt = theta_logits[0];
        for (int k = 1; k < KK; ++k) mt = fmaxf(mt, theta_logits[k]);
        float st = 0.f;
        for (int k = 0; k < KK; ++k) st += __expf(theta_logits[k] - mt);
        lsetp[0] = mt + __logf(st);
    }
}

// ---------------- Kernel 1: encoder via bf16 MFMA ----------------
__global__ __launch_bounds__(256) void encoder_mfma(
    const float* __restrict__ Y,
    const unsigned short* __restrict__ wenc,  // [2][32768] swizzled bf16
    const float* __restrict__ be_mu, const float* __restrict__ be_sig,
    float* __restrict__ enc_mu, float* __restrict__ enc_sig)
{
    const int t = threadIdx.x;
    const int w = t >> 6, lane = t & 63, l16 = lane & 15, quad = lane >> 4;
    const int mat = blockIdx.x & 1;
    const int rt = blockIdx.x >> 1;            // 16-row tile
    const int row = rt * 16 + l16;
    const int ct = w;                          // col tile 0..3
    const unsigned short* Ws = wenc + mat * 32768;
    const float4* Yrow = (const float4*)(Y + (size_t)row * YD);

    const float* bias = mat ? be_sig : be_mu;
    float* outp = mat ? enc_sig : enc_mu;
    const int col = ct * 16 + l16;
    const float bv = bias[col];
    f32x4 acc = (f32x4){bv, bv, bv, bv};

#pragma unroll
    for (int kt = 0; kt < 16; ++kt) {
        float4 y0 = Yrow[kt * 8 + quad * 2];
        float4 y1 = Yrow[kt * 8 + quad * 2 + 1];
        union { short8 s; unsigned int u[4]; } a;
        a.u[0] = pack2_bf16(y0.x, y0.y);
        a.u[1] = pack2_bf16(y0.z, y0.w);
        a.u[2] = pack2_bf16(y1.x, y1.y);
        a.u[3] = pack2_bf16(y1.z, y1.w);
        short8 b = *(const short8*)(Ws + (((kt * 4 + ct) * 4 + quad) * 16 + l16) * 8);
        acc = __builtin_amdgcn_mfma_f32_16x16x32_bf16(a.s, b, acc, 0, 0, 0);
    }

    const int base_row = rt * 16 + quad * 4;
#pragma unroll
    for (int r = 0; r < 4; ++r) {
        float v = acc[r];
        if (mat) v = softplusf(v) + 1e-3f;
        outp[(size_t)(base_row + r) * XD + col] = v;
    }
}

// ---------------- Kernel 2: fused responsibilities + sampling + losses 2/3/4/5 ----------------
// one wave per n
__global__ __launch_bounds__(256, 3) void fused_sample_kernel(
    const float* __restrict__ enc_mu_g, const float* __restrict__ enc_sig_g,
    const float* __restrict__ phi_mus, const float* __restrict__ phi_sigs,
    const float* __restrict__ phi_logits, const float4* __restrict__ tab4,
    const float* __restrict__ theta_logits, const float* __restrict__ lsetp,
    const float* __restrict__ u_noise, const float* __restrict__ eps_noise,
    const float* __restrict__ temperature,
    unsigned short* __restrict__ x_bf16, double* __restrict__ slots)
{
    __shared__ float red234[4], red5[4];
    const int wv = threadIdx.x >> 6;
    const int n = blockIdx.x * 4 + wv;
    const int d = threadIdx.x & 63;
    const int kd = d & 15;
    const int g = d >> 4;

    // ---- responsibilities: lane = (g, kd); partial over dims g*16..g*16+15 ----
    const float4* em4 = (const float4*)(enc_mu_g + (size_t)n * XD + g * 16);
    const float4* es4 = (const float4*)(enc_sig_g + (size_t)n * XD + g * 16);
    const float4* pm4 = (const float4*)(phi_mus + kd * XD + g * 16);
    const float4* ps4 = (const float4*)(phi_sigs + kd * XD + g * 16);

    float part = 0.f;
#pragma unroll
    for (int q = 0; q < 4; ++q) {
        float4 emv = em4[q], esv = es4[q], pmv = pm4[q], psv = ps4[q];
        {
            float sd = esv.x + psv.x; float df = (emv.x - pmv.x) * fast_rcp(sd);
            part += fmaf(-0.5f * df, df, -__logf(sd));
        }
        {
            float sd = esv.y + psv.y; float df = (emv.y - pmv.y) * fast_rcp(sd);
            part += fmaf(-0.5f * df, df, -__logf(sd));
        }
        {
            float sd = esv.z + psv.z; float df = (emv.z - pmv.z) * fast_rcp(sd);
            part += fmaf(-0.5f * df, df, -__logf(sd));
        }
        {
            float sd = esv.w + psv.w; float df = (emv.w - pmv.w) * fast_rcp(sd);
            part += fmaf(-0.5f * df, df, -__logf(sd));
        }
    }
    part += __shfl_xor(part, 16, 64);
    part += __shfl_xor(part, 32, 64);
    float zl = part + phi_logits[kd];

    // log_softmax over k (lane-parallel within 16-groups; zl now 4x replicated)
    float m = zl;
#pragma unroll
    for (int off = 1; off <= 8; off <<= 1) m = fmaxf(m, __shfl_xor(m, off, 64));
    float e0 = __expf(zl - m);
    float s0 = e0;
#pragma unroll
    for (int off = 1; off <= 8; off <<= 1) s0 += __shfl_xor(s0, off, 64);
    zl -= m + __logf(s0);

    // loss5 term
    float m3 = zl;
#pragma unroll
    for (int off = 1; off <= 8; off <<= 1) m3 = fmaxf(m3, __shfl_xor(m3, off, 64));
    float e3 = __expf(zl - m3);
    float s3 = e3;
#pragma unroll
    for (int off = 1; off <= 8; off <<= 1) s3 += __shfl_xor(s3, off, 64);
    float l5 = m3 + __logf(s3);

    // ---- sampling part (identical to r5 sample_kernel, zl in-register) ----
    const float invT = fast_rcp(temperature[0]);
    const float zl_l = zl;
    const float tl_l = theta_logits[kd];
    const float lset = lsetp[0];

    const float em = enc_mu_g[(size_t)n * XD + d];
    const float es = enc_sig_g[(size_t)n * XD + d];
    const float inv_es = fast_rcp(es);
    const float log_es = __logf(es);
    const float em_ie = inv_es * em;

    float mu[KK], Sg[KK], tm[KK], ts[KK], pm[KK], ps[KK];
#pragma unroll
    for (int k = 0; k < KK; ++k) {
        float4 tb = tab4[k * XD + d];     // {phi_mu, phi_sig, th_mu, th_sig}
        pm[k] = tb.x; ps[k] = tb.y; tm[k] = tb.z; ts[k] = tb.w;
        float ig = fast_rcp(tb.y);
        Sg[k] = fast_rcp(inv_es + ig);
        mu[k] = Sg[k] * fmaf(ig, tb.x, em_ie);
    }

    float eP[3], dzP[3], dthP[3];
#pragma unroll
    for (int p = 0; p < 3; ++p) {
        int sp = p * 4 + g;
        int spc = sp < SS ? sp : 0;       // clamp (results unused)
        float u = u_noise[((size_t)n * SS + spc) * KK + kd];
        float lg = (zl_l - __logf(-__logf(u))) * invT;
        float mg = lg;
        mg = fmaxf(mg, __shfl_xor(mg, 1, 64));
        mg = fmaxf(mg, __shfl_xor(mg, 2, 64));
        mg = fmaxf(mg, __shfl_xor(mg, 4, 64));
        mg = fmaxf(mg, __shfl_xor(mg, 8, 64));
        float e = __expf(lg - mg);
        float zs = e;
        zs += __shfl_xor(zs, 1, 64);
        zs += __shfl_xor(zs, 2, 64);
        zs += __shfl_xor(zs, 4, 64);
        zs += __shfl_xor(zs, 8, 64);
        e *= fast_rcp(zs);                 // normalized weight
        float pz = e * zl_l, pt = e * tl_l;
#pragma unroll
        for (int off = 1; off <= 8; off <<= 1) {
            pz += __shfl_xor(pz, off, 64);
            pt += __shfl_xor(pt, off, 64);
        }
        eP[p] = e; dzP[p] = pz; dthP[p] = pt;
    }

    float r_acc = 0.f, sc_acc = 0.f;
    const float* erow = eps_noise + (size_t)n * SS * XD + d;
    unsigned short* xrow = x_bf16 + (size_t)n * SS * XD + d;

#pragma unroll
    for (int s = 0; s < SS; ++s) {
        const int p = s >> 2, L = (s & 3) * 16;
        float ms = 0.f, Ssum = 0.f, tmu = 0.f, tsig = 0.f, pmu = 0.f, psig = 0.f;
#pragma unroll
        for (int k = 0; k < KK; ++k) {
            float ek = bcast(eP[p], L + k);
            ms   = fmaf(ek, mu[k], ms);
            Ssum = fmaf(ek, Sg[k], Ssum);
            tmu  = fmaf(ek, tm[k], tmu);
            tsig = fmaf(ek, ts[k], tsig);
            pmu  = fmaf(ek, pm[k], pmu);
            psig = fmaf(ek, ps[k], psig);
        }
        float ep = erow[s * XD];
        float x = fmaf(__builtin_amdgcn_sqrtf(Ssum), ep, ms);
        xrow[s * XD] = f32_to_bf16(x);

        float de  = (x - em) * inv_es;
        float rts = fast_rcp(tsig);
        float dt2 = (x - tmu) * rts;
        float dp  = (x - pmu) * fast_rcp(psig);
        r_acc += 0.5f * (de * de - dt2 * dt2 + dp * dp) + __logf(psig * rts);
        sc_acc += bcast(dthP[p], L) - bcast(dzP[p], L);
    }

    r_acc = fmaf((float)SS, log_es, r_acc);
    r_acc = wave_sum(r_acc);

    const float C234 = 0.5f * XD * 1.8378770664093453f;
    float total = r_acc + sc_acc + (float)SS * (C234 - lset);

    if (d == 0) { red234[wv] = total; red5[wv] = l5; }
    __syncthreads();
    if (threadIdx.x == 0) {
        atomicAdd(slots + (blockIdx.x & 63),
                  (double)(red234[0] + red234[1] + red234[2] + red234[3]));
        atomicAdd(slots + 64 + (blockIdx.x & 63),
                  (double)(red5[0] + red5[1] + red5[2] + red5[3]));
    }
}

// ---------------- Kernel 3: decoder via bf16 MFMA + fused loss1 ----------------
// grid dim3(NS/128, YD/64); block 256 = 4 waves; wave tile 32 rows x 64 cols
__global__ __launch_bounds__(256) void decoder_mfma(
    const unsigned short* __restrict__ xb,
    const unsigned short* __restrict__ wmu_s,
    const unsigned short* __restrict__ wsg_s,
    const float* __restrict__ bd_mu, const float* __restrict__ bd_sig,
    const float* __restrict__ Y, double* __restrict__ slots1,
    unsigned int magicS)
{
    __shared__ float red[4];
    const int t = threadIdx.x;
    const int w = t >> 6;
    const int lane = t & 63;
    const int l16 = lane & 15;
    const int quad = lane >> 4;
    const int mb = blockIdx.x;
    const int nb = blockIdx.y;

    const int row0 = mb * 128 + w * 32;

    short8 a[2][2];
#pragma unroll
    for (int rg = 0; rg < 2; ++rg) {
        const unsigned short* xp = xb + (size_t)(row0 + rg * 16 + l16) * XD + quad * 8;
        a[rg][0] = *(const short8*)xp;
        a[rg][1] = *(const short8*)(xp + 32);
    }

    f32x4 accmu[2][4], accsg[2][4];
#pragma unroll
    for (int tt = 0; tt < 4; ++tt) {
        int col = nb * 64 + tt * 16 + l16;
        float bm = bd_mu[col], bs = bd_sig[col];
#pragma unroll
        for (int rg = 0; rg < 2; ++rg) {
            accmu[rg][tt] = (f32x4){bm, bm, bm, bm};
            accsg[rg][tt] = (f32x4){bs, bs, bs, bs};
        }
    }

#pragma unroll
    for (int tt = 0; tt < 4; ++tt) {
        int tg = nb * 4 + tt;
        int boff = ((tg * 8 + quad) * 16 + l16) * 8;
        short8 b0 = *(const short8*)(wmu_s + boff);
        short8 b1 = *(const short8*)(wmu_s + boff + 512);
        short8 c0 = *(const short8*)(wsg_s + boff);
        short8 c1 = *(const short8*)(wsg_s + boff + 512);
#pragma unroll
        for (int rg = 0; rg < 2; ++rg) {
            accmu[rg][tt] = __builtin_amdgcn_mfma_f32_16x16x32_bf16(a[rg][0], b0, accmu[rg][tt], 0, 0, 0);
            accmu[rg][tt] = __builtin_amdgcn_mfma_f32_16x16x32_bf16(a[rg][1], b1, accmu[rg][tt], 0, 0, 0);
            accsg[rg][tt] = __builtin_amdgcn_mfma_f32_16x16x32_bf16(a[rg][0], c0, accsg[rg][tt], 0, 0, 0);
            accsg[rg][tt] = __builtin_amdgcn_mfma_f32_16x16x32_bf16(a[rg][1], c1, accsg[rg][tt], 0, 0, 0);
        }
    }

    float part = 0.f;
#pragma unroll
    for (int rg = 0; rg < 2; ++rg) {
        const int m_base = row0 + rg * 16 + quad * 4;
#pragma unroll
        for (int r = 0; r < 4; ++r) {
            int row = m_base + r;
            unsigned int ny = (unsigned int)(((unsigned long long)(unsigned int)row * magicS) >> 35);
            const float* Yr = Y + (size_t)ny * YD + nb * 64 + l16;
            float prod = 1.0f;
#pragma unroll
            for (int tt = 0; tt < 4; ++tt) {
                float Yv = Yr[tt * 16];
                float sig = softplusf(accsg[rg][tt][r]) + 1e-3f;
                float diff = (Yv - accmu[rg][tt][r]) * fast_rcp(sig);
                part = fmaf(-0.5f * diff, diff, part);
                prod *= sig;
            }
            part -= __logf(prod);     // = sum log(sig); range sig^4 in [1e-12,1e4]
        }
    }
    part = wave_sum(part);
    if (lane == 0) red[w] = part;
    __syncthreads();
    if (t == 0) {
        atomicAdd(slots1 + ((blockIdx.y * gridDim.x + blockIdx.x) & 63),
                  (double)(red[0] + red[1] + red[2] + red[3]));
    }
}

// ---------------- Kernel 4: finalize ----------------
__global__ void finalize_kernel(const double* __restrict__ slots,
                                float* __restrict__ out, int NS, int S)
{
    double l234 = 0.0, l5 = 0.0, l1 = 0.0;
    for (int i = 0; i < 64; ++i) {
        l234 += slots[i];
        l5   += slots[64 + i];
        l1   += slots[128 + i];
    }
    l1 += (double)NS * (-0.5 * (double)YD * 1.8378770664093453);
    out[0] = (float)(-((l1 + l234) / (double)S + l5));
}

extern "C" void kernel_launch(void* const* d_in, const int* in_sizes, int n_in,
                              void* d_out, int out_size, void* d_ws, size_t ws_size,
                              hipStream_t stream) {
    const float* Y            = (const float*)d_in[0];
    const float* We_mu        = (const float*)d_in[1];
    const float* be_mu        = (const float*)d_in[2];
    const float* We_sig       = (const float*)d_in[3];
    const float* be_sig       = (const float*)d_in[4];
    const float* Wd_mu        = (const float*)d_in[5];
    const float* bd_mu        = (const float*)d_in[6];
    const float* Wd_sig       = (const float*)d_in[7];
    const float* bd_sig       = (const float*)d_in[8];
    const float* phi_mus      = (const float*)d_in[9];
    const float* phi_sigs     = (const float*)d_in[10];
    const float* phi_logits   = (const float*)d_in[11];
    const float* theta_mus    = (const float*)d_in[12];
    const float* theta_sigs   = (const float*)d_in[13];
    const float* theta_logits = (const float*)d_in[14];
    const float* u_noise      = (const float*)d_in[15];
    const float* eps_noise    = (const float*)d_in[16];
    const float* temperature  = (const float*)d_in[17];

    const int N = in_sizes[0] / YD;           // 8192
    const int S = in_sizes[15] / (N * KK);    // 10 (== SS)
    const int NS = N * S;
    const unsigned int magicS =
        (unsigned int)((((unsigned long long)1 << 35) + S - 1) / (unsigned long long)S);

    char* base = (char*)d_ws;
    double* slots = (double*)base;                       // 192 doubles (3 x 64)
    float* enc_mu  = (float*)(base + 2048);
    float* enc_sig = enc_mu + (size_t)N * XD;
    float* zlp     = enc_sig + (size_t)N * XD;           // (unused, layout kept)
    float4* tab4   = (float4*)(zlp + (size_t)N * KK);    // 1024 float4
    float* lsetp   = (float*)(tab4 + 1024);
    unsigned short* xb    = (unsigned short*)(lsetp + 16);
    unsigned short* wmu_s = xb + (size_t)NS * XD;
    unsigned short* wsg_s = wmu_s + 32768;
    unsigned short* wenc  = wsg_s + 32768;               // 2 x 32768

    hipMemsetAsync(slots, 0, 2048, stream);

    prep_kernel<<<517, 256, 0, stream>>>(Wd_mu, Wd_sig, We_mu, We_sig,
                                         phi_mus, phi_sigs, theta_mus,
                                         theta_sigs, theta_logits,
                                         wmu_s, wsg_s, wenc, tab4, lsetp);
    encoder_mfma<<<(N / 16) * 2, 256, 0, stream>>>(Y, wenc, be_mu, be_sig,
                                                   enc_mu, enc_sig);
    fused_sample_kernel<<<N / 4, 256, 0, stream>>>(enc_mu, enc_sig,
                                                   phi_mus, phi_sigs, phi_logits,
                                                   tab4, theta_logits, lsetp,
                                                   u_noise, eps_noise, temperature,
                                                   xb, slots);
    decoder_mfma<<<dim3(NS / 128, YD / 64), 256, 0, stream>>>(
        xb, wmu_s, wsg_s, bd_mu, bd_sig, Y, slots + 128, magicS);
    finalize_kernel<<<1, 1, 0, stream>>>(slots, (float*)d_out, NS, S);
}